// Round 3
// baseline (1222.787 us; speedup 1.0000x reference)
//
#include <hip/hip_runtime.h>
#include <hip/hip_bf16.h>
#include <cstdint>
#include <cstddef>

#define N_NODES 100000
#define E_EDGES 6400000
#define E_TOT   (E_EDGES + N_NODES)
#define IN_CH   128
#define NHID    16              // HEADS*HID
#define BSHIFT  9               // 512 dsts per bucket
#define BSZ     512
#define NBUCK   196             // ceil(100000/512)
#define CHUNK   6144            // edges per k_bin block
#define BCAP    72              // LDS staging capacity per bucket (mean 31.5)
#define NCHUNK  ((E_TOT + CHUNK - 1) / CHUNK)   // 1058

// ---------------- detection: int64 vs int32 edge_index ----------------
__global__ void k_detect(const int* __restrict__ edge, int* __restrict__ flag) {
    if (blockIdx.x == 0 && threadIdx.x == 0) {
        int odd_or = 0;
        for (int i = 0; i < 64; i++) odd_or |= edge[2 * i + 1];
        flag[0] = (odd_or == 0) ? 1 : 0;   // 1 => data is int64 little-endian
    }
}

__device__ __forceinline__ int load_src(const int* e, size_t i, int m64) {
    return m64 ? e[2 * i] : e[i];
}
__device__ __forceinline__ int load_dst(const int* e, size_t i, int m64) {
    return m64 ? e[2 * ((size_t)E_EDGES + i)] : e[(size_t)E_EDGES + i];
}

// ---------------- layer-1 node features: h1 = x@W1 (NO bias), alphas --
__global__ __launch_bounds__(256) void k_gemm1(
        const float* __restrict__ x, const float* __restrict__ W1,
        const float* __restrict__ a_src1, const float* __restrict__ a_dst1,
        float* __restrict__ h1, float* __restrict__ alpha1) {
    __shared__ __align__(16) float sW[IN_CH * NHID];   // 8 KB
    __shared__ __align__(16) float sx[16][132];        // padded stride
    __shared__ float sh[16][17];
    int t = threadIdx.x;
    int r = t >> 4, c = t & 15;
    int row = blockIdx.x * 16 + r;

    const float4* W4 = (const float4*)W1;
    ((float4*)sW)[t] = W4[t];
    ((float4*)sW)[t + 256] = W4[t + 256];

    if (row < N_NODES) {
        const float4* xr = (const float4*)(x + (size_t)row * IN_CH);
        float4 v0 = xr[c];
        float4 v1 = xr[c + 16];
        *(float4*)&sx[r][4 * c] = v0;
        *(float4*)&sx[r][64 + 4 * c] = v1;
    }
    __syncthreads();

    float acc = 0.f;
    if (row < N_NODES) {
        #pragma unroll 16
        for (int k = 0; k < IN_CH; k++) acc = fmaf(sx[r][k], sW[k * NHID + c], acc);
        h1[(size_t)row * NHID + c] = acc;
    }
    sh[r][c] = acc;
    __syncthreads();

    if (row < N_NODES && c < 4) {
        int h = c & 1;
        const float* av = (c >= 2) ? a_dst1 : a_src1;
        float s = 0.f;
        #pragma unroll
        for (int q = 0; q < 8; q++) s = fmaf(sh[r][h * 8 + q], av[h * 8 + q], s);
        alpha1[(size_t)row * 4 + c] = s;   // [as0, as1, ad0, ad1]
    }
}

// ---------------- bucket count (196 coarse counters) ----------------
__global__ __launch_bounds__(256) void k_bcount(const int* __restrict__ edge,
                                                const int* __restrict__ flag,
                                                int* __restrict__ bcnt) {
    __shared__ int sc[NBUCK];
    int m64 = flag[0];
    int t = threadIdx.x;
    for (int i = t; i < NBUCK; i += 256) sc[i] = 0;
    __syncthreads();
    size_t stride = (size_t)gridDim.x * 256;
    for (size_t i = (size_t)blockIdx.x * 256 + t; i < E_TOT; i += stride) {
        int d = (i < E_EDGES) ? load_dst(edge, i, m64) : (int)(i - E_EDGES);
        atomicAdd(&sc[d >> BSHIFT], 1);
    }
    __syncthreads();
    for (int i = t; i < NBUCK; i += 256) if (sc[i]) atomicAdd(&bcnt[i], sc[i]);
}

// ---------------- tiny scan over 196 buckets ----------------
__global__ void k_bscan(const int* __restrict__ bcnt, int* __restrict__ bbase,
                        int* __restrict__ bcur) {
    __shared__ int sd[256];
    int t = threadIdx.x;
    int v = (t < NBUCK) ? bcnt[t] : 0;
    sd[t] = v;
    __syncthreads();
    for (int ofs = 1; ofs < 256; ofs <<= 1) {
        int a = sd[t];
        int b = (t >= ofs) ? sd[t - ofs] : 0;
        __syncthreads();
        sd[t] = a + b;
        __syncthreads();
    }
    if (t < NBUCK) {
        int e = sd[t] - v;          // exclusive
        bbase[t] = e;
        bcur[t]  = e;
    }
    if (t == NBUCK) bbase[NBUCK] = sd[NBUCK - 1];
}

// ---------------- binning: coalesced (src | dlocal<<17) u32 stream ----
__global__ __launch_bounds__(256) void k_bin(const int* __restrict__ edge,
                                             const int* __restrict__ flag,
                                             int* __restrict__ bcur,
                                             unsigned* __restrict__ staged) {
    __shared__ unsigned lbin[NBUCK][BCAP];   // 55 KB
    __shared__ int lcnt[NBUCK];
    __shared__ int lpos[NBUCK];
    int m64 = flag[0];
    int t = threadIdx.x;
    int g = t >> 4, lane = t & 15;

    size_t c0 = (size_t)blockIdx.x * CHUNK;
    if (c0 >= E_TOT) return;
    size_t cend = c0 + CHUNK;
    if (cend > E_TOT) cend = E_TOT;

    for (int i = t; i < NBUCK; i += 256) lcnt[i] = 0;
    __syncthreads();

    for (size_t i = c0 + t; i < cend; i += 256) {
        int s, d;
        if (i < E_EDGES) { s = load_src(edge, i, m64); d = load_dst(edge, i, m64); }
        else             { s = d = (int)(i - E_EDGES); }
        int b = d >> BSHIFT;
        unsigned v = (unsigned)s | ((unsigned)(d & (BSZ - 1)) << 17);
        int idx = atomicAdd(&lcnt[b], 1);
        if (idx < BCAP) lbin[b][idx] = v;
        else {                                  // overflow: correct slow path
            int pos = atomicAdd(&bcur[b], 1);
            staged[pos] = v;
        }
    }
    __syncthreads();
    for (int b = t; b < NBUCK; b += 256) {
        int n = min(lcnt[b], BCAP);
        if (n) lpos[b] = atomicAdd(&bcur[b], n);
    }
    __syncthreads();
    // cooperative coalesced flush: 16 lane-groups sweep buckets
    for (int b = g; b < NBUCK; b += 16) {
        int n = min(lcnt[b], BCAP);
        if (!n) continue;
        int pos = lpos[b];
        for (int i = lane; i < n; i += 16) staged[pos + i] = lbin[b][i];
    }
}

// ---------------- layer-1 aggregation: per-bucket LDS softmax state ---
// grid = NBUCK*2; block handles half of one bucket's edges.
__global__ __launch_bounds__(256) void k_edge1(
        const unsigned* __restrict__ staged, const int* __restrict__ bbase,
        const float* __restrict__ h1, const float* __restrict__ alpha1,
        float* __restrict__ gacc1) {
    __shared__ float acc[BSZ][18];    // 16 ch + den0 + den1   (36.9 KB)
    __shared__ float adp[BSZ][2];
    int bkt = blockIdx.x >> 1, p = blockIdx.x & 1;
    int t = threadIdx.x;
    int dbase = bkt << BSHIFT;

    for (int i = t; i < BSZ * 18; i += 256) ((float*)acc)[i] = 0.f;
    for (int i = t; i < BSZ; i += 256) {
        int d = dbase + i;
        float2 v = (d < N_NODES) ? ((const float2*)alpha1)[2 * (size_t)d + 1]
                                 : make_float2(0.f, 0.f);
        adp[i][0] = v.x; adp[i][1] = v.y;
    }
    __syncthreads();

    int beg = bbase[bkt], end = bbase[bkt + 1];
    int n = end - beg, half = (n + 1) >> 1;
    int lo = beg + p * half;
    int hi = lo + half; if (hi > end) hi = end;

    int g = t >> 4, lane = t & 15;
    for (int e = lo + g; e < hi; e += 16) {
        unsigned v = staged[e];
        int s  = (int)(v & 0x1FFFFu);
        int dl = (int)(v >> 17);
        float2 asp = *(const float2*)(alpha1 + 4 * (size_t)s);
        float a0 = asp.x + adp[dl][0]; a0 = (a0 > 0.f) ? a0 : 0.2f * a0;
        float a1 = asp.y + adp[dl][1]; a1 = (a1 > 0.f) ? a1 : 0.2f * a1;
        float p0 = __expf(a0), p1 = __expf(a1);
        float hv = h1[(size_t)s * NHID + lane];     // one 64B line per edge
        atomicAdd(&acc[dl][lane], ((lane < 8) ? p0 : p1) * hv);
        if (lane == 0) atomicAdd(&acc[dl][16], p0);
        if (lane == 1) atomicAdd(&acc[dl][17], p1);
    }
    __syncthreads();
    int gmax = min(dbase + BSZ, N_NODES) - dbase;
    for (int i = t; i < gmax * 18; i += 256) {
        float v = ((float*)acc)[i];
        if (v != 0.f) atomicAdd(&gacc1[(size_t)dbase * 18 + i], v);
    }
}

// ---------------- layer-1 epilogue: softmax-div + bias + ReLU + @W2 ---
__global__ __launch_bounds__(256) void k_ep1(const float* __restrict__ gacc1,
                                             const float* __restrict__ b1,
                                             const float* __restrict__ W2,
                                             float* __restrict__ h2) {
    int t = threadIdx.x;
    int g = t >> 4, lane = t & 15;
    int d = blockIdx.x * 16 + g;
    if (d >= N_NODES) return;
    const float* a = gacc1 + (size_t)d * 18;
    float den = a[16 + (lane >> 3)];
    float o = a[lane] / (den + 1e-16f) + b1[lane];
    o = (o > 0.f) ? o : 0.f;
    float v = o * W2[lane];
    v += __shfl_xor(v, 1, 64);
    v += __shfl_xor(v, 2, 64);
    v += __shfl_xor(v, 4, 64);
    v += __shfl_xor(v, 8, 64);
    if (lane == 0) h2[d] = v;
}

// ---------------- layer-2 aggregation ----------------
__global__ __launch_bounds__(256) void k_edge2(
        const unsigned* __restrict__ staged, const int* __restrict__ bbase,
        const float* __restrict__ h2,
        const float* __restrict__ a_src2, const float* __restrict__ a_dst2,
        float* __restrict__ gacc2) {
    __shared__ float acc2[BSZ][2];
    __shared__ float hds[BSZ];
    int bkt = blockIdx.x >> 1, p = blockIdx.x & 1;
    int t = threadIdx.x;
    int dbase = bkt << BSHIFT;
    float as2 = a_src2[0], ad2 = a_dst2[0];

    for (int i = t; i < BSZ; i += 256) {
        acc2[i][0] = 0.f; acc2[i][1] = 0.f;
        int d = dbase + i;
        hds[i] = (d < N_NODES) ? h2[d] * ad2 : 0.f;
    }
    __syncthreads();

    int beg = bbase[bkt], end = bbase[bkt + 1];
    int n = end - beg, half = (n + 1) >> 1;
    int lo = beg + p * half;
    int hi = lo + half; if (hi > end) hi = end;

    for (int e = lo + t; e < hi; e += 256) {
        unsigned v = staged[e];
        int s  = (int)(v & 0x1FFFFu);
        int dl = (int)(v >> 17);
        float hs = h2[s];
        float a = fmaf(hs, as2, hds[dl]);
        a = (a > 0.f) ? a : 0.2f * a;
        float pw = __expf(a);
        atomicAdd(&acc2[dl][0], pw);
        atomicAdd(&acc2[dl][1], pw * hs);
    }
    __syncthreads();
    int gmax = min(dbase + BSZ, N_NODES) - dbase;
    for (int i = t; i < gmax * 2; i += 256) {
        float v = ((float*)acc2)[i];
        if (v != 0.f) atomicAdd(&gacc2[(size_t)dbase * 2 + i], v);
    }
}

// ---------------- layer-2 epilogue ----------------
__global__ __launch_bounds__(256) void k_ep2(const float* __restrict__ gacc2,
                                             const float* __restrict__ b2,
                                             float* __restrict__ out) {
    int d = blockIdx.x * 256 + threadIdx.x;
    if (d < N_NODES) out[d] = gacc2[2 * (size_t)d + 1] / (gacc2[2 * (size_t)d] + 1e-16f) + b2[0];
}

// ---------------- launch ----------------
extern "C" void kernel_launch(void* const* d_in, const int* in_sizes, int n_in,
                              void* d_out, int out_size, void* d_ws, size_t ws_size,
                              hipStream_t stream) {
    const float* x      = (const float*)d_in[0];
    const int*   edge   = (const int*)  d_in[1];
    const float* W1     = (const float*)d_in[2];
    const float* a_src1 = (const float*)d_in[3];
    const float* a_dst1 = (const float*)d_in[4];
    const float* b1     = (const float*)d_in[5];
    const float* W2     = (const float*)d_in[6];
    const float* a_src2 = (const float*)d_in[7];
    const float* a_dst2 = (const float*)d_in[8];
    const float* b2     = (const float*)d_in[9];

    constexpr size_t A = 256;
    auto al = [](size_t b) { return (b + A - 1) / A * A; };
    char* ws = (char*)d_ws;
    size_t off = 0;
    int*      flag   = (int*)(ws + off);      off += al(256);
    int*      bcnt   = (int*)(ws + off);      off += al(NBUCK * 4);
    int*      bbase  = (int*)(ws + off);      off += al((NBUCK + 1) * 4);
    int*      bcur   = (int*)(ws + off);      off += al(NBUCK * 4);
    unsigned* staged = (unsigned*)(ws + off); off += al((size_t)E_TOT * 4);       // 26 MB
    float*    h1     = (float*)(ws + off);    off += al((size_t)N_NODES * NHID * 4); // 6.4 MB
    float*    alpha1 = (float*)(ws + off);    off += al((size_t)N_NODES * 4 * 4);    // 1.6 MB
    float*    h2     = (float*)(ws + off);    off += al((size_t)N_NODES * 4);
    float*    gacc1  = (float*)(ws + off);    off += al((size_t)N_NODES * 18 * 4);   // 7.2 MB
    float*    gacc2  = (float*)(ws + off);    off += al((size_t)N_NODES * 2 * 4);    // 0.8 MB
    (void)ws_size; (void)in_sizes; (void)n_in; (void)out_size;

    hipMemsetAsync(bcnt, 0, NBUCK * 4, stream);
    hipMemsetAsync(gacc1, 0, (size_t)N_NODES * 20 * 4, stream);  // gacc1+gacc2 adjacent

    k_detect<<<1, 64, 0, stream>>>(edge, flag);
    k_gemm1 <<<(N_NODES + 15) / 16, 256, 0, stream>>>(x, W1, a_src1, a_dst1, h1, alpha1);
    k_bcount<<<2048, 256, 0, stream>>>(edge, flag, bcnt);
    k_bscan <<<1, 256, 0, stream>>>(bcnt, bbase, bcur);
    k_bin   <<<NCHUNK, 256, 0, stream>>>(edge, flag, bcur, staged);
    k_edge1 <<<NBUCK * 2, 256, 0, stream>>>(staged, bbase, h1, alpha1, gacc1);
    k_ep1   <<<(N_NODES + 15) / 16, 256, 0, stream>>>(gacc1, b1, W2, h2);
    k_edge2 <<<NBUCK * 2, 256, 0, stream>>>(staged, bbase, h2, a_src2, a_dst2, gacc2);
    k_ep2   <<<(N_NODES + 255) / 256, 256, 0, stream>>>(gacc2, b2, (float*)d_out);
}

// Round 4
// 476.231 us; speedup vs baseline: 2.5676x; 2.5676x over previous
//
#include <hip/hip_runtime.h>
#include <hip/hip_fp16.h>
#include <cstdint>
#include <cstddef>

#define N_NODES 100000
#define E_EDGES 6400000
#define E_TOT   (E_EDGES + N_NODES)
#define IN_CH   128
#define NHID    16              // HEADS*HID
#define BSHIFT  9               // 512 dsts per bucket
#define BSZ     512
#define NBUCK   196             // ceil(100000/512)
#define CHUNK   6144            // edges per k_bin block
#define BCAP    72              // LDS staging capacity per bucket (mean 31.5)
#define NCHUNK  ((E_TOT + CHUNK - 1) / CHUNK)   // 1058

// ---------------- detection: int64 vs int32 edge_index ----------------
__global__ void k_detect(const int* __restrict__ edge, int* __restrict__ flag) {
    if (blockIdx.x == 0 && threadIdx.x == 0) {
        int odd_or = 0;
        for (int i = 0; i < 64; i++) odd_or |= edge[2 * i + 1];
        flag[0] = (odd_or == 0) ? 1 : 0;   // 1 => data is int64 little-endian
    }
}

__device__ __forceinline__ int load_src(const int* e, size_t i, int m64) {
    return m64 ? e[2 * i] : e[i];
}
__device__ __forceinline__ int load_dst(const int* e, size_t i, int m64) {
    return m64 ? e[2 * ((size_t)E_EDGES + i)] : e[(size_t)E_EDGES + i];
}

// ------- layer-1 node features: h16 = fp16(x@W1), split alpha arrays --
__global__ __launch_bounds__(256) void k_gemm1(
        const float* __restrict__ x, const float* __restrict__ W1,
        const float* __restrict__ a_src1, const float* __restrict__ a_dst1,
        __half* __restrict__ h16, float* __restrict__ asrc,
        float* __restrict__ adst) {
    __shared__ __align__(16) float sW[IN_CH * NHID];   // 8 KB
    __shared__ __align__(16) float sx[16][132];        // padded stride
    __shared__ float sh[16][17];
    int t = threadIdx.x;
    int r = t >> 4, c = t & 15;
    int row = blockIdx.x * 16 + r;

    const float4* W4 = (const float4*)W1;
    ((float4*)sW)[t] = W4[t];
    ((float4*)sW)[t + 256] = W4[t + 256];

    if (row < N_NODES) {
        const float4* xr = (const float4*)(x + (size_t)row * IN_CH);
        float4 v0 = xr[c];
        float4 v1 = xr[c + 16];
        *(float4*)&sx[r][4 * c] = v0;
        *(float4*)&sx[r][64 + 4 * c] = v1;
    }
    __syncthreads();

    float acc = 0.f;
    if (row < N_NODES) {
        #pragma unroll 16
        for (int k = 0; k < IN_CH; k++) acc = fmaf(sx[r][k], sW[k * NHID + c], acc);
        h16[(size_t)row * NHID + c] = __float2half(acc);
    }
    sh[r][c] = acc;
    __syncthreads();

    if (row < N_NODES && c < 4) {
        int h = c & 1;
        const float* av = (c >= 2) ? a_dst1 : a_src1;
        float s = 0.f;
        #pragma unroll
        for (int q = 0; q < 8; q++) s = fmaf(sh[r][h * 8 + q], av[h * 8 + q], s);
        if (c < 2) asrc[2 * (size_t)row + c] = s;
        else       adst[2 * (size_t)row + (c - 2)] = s;
    }
}

// ---------------- bucket count (196 coarse counters) ----------------
__global__ __launch_bounds__(256) void k_bcount(const int* __restrict__ edge,
                                                const int* __restrict__ flag,
                                                int* __restrict__ bcnt) {
    __shared__ int sc[NBUCK];
    int m64 = flag[0];
    int t = threadIdx.x;
    for (int i = t; i < NBUCK; i += 256) sc[i] = 0;
    __syncthreads();
    size_t stride = (size_t)gridDim.x * 256;
    for (size_t i = (size_t)blockIdx.x * 256 + t; i < E_TOT; i += stride) {
        int d = (i < E_EDGES) ? load_dst(edge, i, m64) : (int)(i - E_EDGES);
        atomicAdd(&sc[d >> BSHIFT], 1);
    }
    __syncthreads();
    for (int i = t; i < NBUCK; i += 256) if (sc[i]) atomicAdd(&bcnt[i], sc[i]);
}

// ---------------- tiny scan over 196 buckets ----------------
__global__ void k_bscan(const int* __restrict__ bcnt, int* __restrict__ bbase,
                        int* __restrict__ bcur) {
    __shared__ int sd[256];
    int t = threadIdx.x;
    int v = (t < NBUCK) ? bcnt[t] : 0;
    sd[t] = v;
    __syncthreads();
    for (int ofs = 1; ofs < 256; ofs <<= 1) {
        int a = sd[t];
        int b = (t >= ofs) ? sd[t - ofs] : 0;
        __syncthreads();
        sd[t] = a + b;
        __syncthreads();
    }
    if (t < NBUCK) {
        int e = sd[t] - v;          // exclusive
        bbase[t] = e;
        bcur[t]  = e;
    }
    if (t == NBUCK) bbase[NBUCK] = sd[NBUCK - 1];
}

// ---------------- binning: coalesced (src | dlocal<<17) u32 stream ----
__global__ __launch_bounds__(256) void k_bin(const int* __restrict__ edge,
                                             const int* __restrict__ flag,
                                             int* __restrict__ bcur,
                                             unsigned* __restrict__ staged) {
    __shared__ unsigned lbin[NBUCK][BCAP];   // 55 KB
    __shared__ int lcnt[NBUCK];
    __shared__ int lpos[NBUCK];
    int m64 = flag[0];
    int t = threadIdx.x;
    int g = t >> 4, lane = t & 15;

    size_t c0 = (size_t)blockIdx.x * CHUNK;
    if (c0 >= E_TOT) return;
    size_t cend = c0 + CHUNK;
    if (cend > E_TOT) cend = E_TOT;

    for (int i = t; i < NBUCK; i += 256) lcnt[i] = 0;
    __syncthreads();

    for (size_t i = c0 + t; i < cend; i += 256) {
        int s, d;
        if (i < E_EDGES) { s = load_src(edge, i, m64); d = load_dst(edge, i, m64); }
        else             { s = d = (int)(i - E_EDGES); }
        int b = d >> BSHIFT;
        unsigned v = (unsigned)s | ((unsigned)(d & (BSZ - 1)) << 17);
        int idx = atomicAdd(&lcnt[b], 1);
        if (idx < BCAP) lbin[b][idx] = v;
        else {                                  // overflow: correct slow path
            int pos = atomicAdd(&bcur[b], 1);
            staged[pos] = v;
        }
    }
    __syncthreads();
    for (int b = t; b < NBUCK; b += 256) {
        int n = min(lcnt[b], BCAP);
        if (n) lpos[b] = atomicAdd(&bcur[b], n);
    }
    __syncthreads();
    // cooperative coalesced flush: 16 lane-groups sweep buckets
    for (int b = g; b < NBUCK; b += 16) {
        int n = min(lcnt[b], BCAP);
        if (!n) continue;
        int pos = lpos[b];
        for (int i = lane; i < n; i += 16) staged[pos + i] = lbin[b][i];
    }
}

// ------- per-bucket exact counting sort -> CSR (L2-local scatter) -----
__global__ __launch_bounds__(1024) void k_sort(const unsigned* __restrict__ staged,
                                               const int* __restrict__ bbase,
                                               int* __restrict__ csr,
                                               int* __restrict__ offs) {
    __shared__ int hist[BSZ];
    __shared__ int lcur[BSZ];
    int bkt = blockIdx.x;
    int t = threadIdx.x;
    int beg = bbase[bkt], end = bbase[bkt + 1];
    int dbase = bkt << BSHIFT;

    if (t < BSZ) hist[t] = 0;
    __syncthreads();
    for (int e = beg + t; e < end; e += 1024)
        atomicAdd(&hist[staged[e] >> 17], 1);
    __syncthreads();

    int myv = (t < BSZ) ? hist[t] : 0;
    __syncthreads();
    for (int ofs = 1; ofs < BSZ; ofs <<= 1) {
        int a = 0, b = 0;
        if (t < BSZ) { a = hist[t]; b = (t >= ofs) ? hist[t - ofs] : 0; }
        __syncthreads();
        if (t < BSZ) hist[t] = a + b;
        __syncthreads();
    }
    if (t < BSZ) {
        int excl = hist[t] - myv;
        lcur[t] = excl;
        int dd = dbase + t;
        if (dd < N_NODES) offs[dd] = beg + excl;
    }
    if (bkt == NBUCK - 1 && t == 0) offs[N_NODES] = E_TOT;
    __syncthreads();

    for (int e = beg + t; e < end; e += 1024) {
        unsigned v = staged[e];
        int pos = atomicAdd(&lcur[v >> 17], 1);
        csr[beg + pos] = (int)(v & 0x1FFFFu);   // 133 KB window: L2-resident
    }
}

// --- layer-1 edge pass: CSR walk, fused softmax + bias + ReLU + @W2 ---
__global__ __launch_bounds__(256) void k_edge1(
        const int* __restrict__ offs, const int* __restrict__ csr,
        const __half* __restrict__ h16, const float* __restrict__ asrc,
        const float* __restrict__ adst,
        const float* __restrict__ b1, const float* __restrict__ W2,
        float* __restrict__ h2out) {
    int t = threadIdx.x;
    int g = t >> 4, lane = t & 15;
    int d = blockIdx.x * 16 + g;
    if (d >= N_NODES) return;

    float2 adp = ((const float2*)adst)[d];
    int beg = offs[d], end = offs[d + 1];

    float acc = 0.f, den0 = 0.f, den1 = 0.f;
    int s = csr[beg];
    float2 asp = ((const float2*)asrc)[s];
    float hv = __half2float(h16[(size_t)s * NHID + lane]);
    for (int e = beg; e < end; e++) {
        // issue next-edge gathers before current exp/fma chain
        int sn = (e + 1 < end) ? csr[e + 1] : 0;
        float2 aspn = ((const float2*)asrc)[sn];
        float hvn = __half2float(h16[(size_t)sn * NHID + lane]);
        float a0 = asp.x + adp.x; a0 = (a0 > 0.f) ? a0 : 0.2f * a0;
        float a1 = asp.y + adp.y; a1 = (a1 > 0.f) ? a1 : 0.2f * a1;
        float p0 = __expf(a0), p1 = __expf(a1);
        acc = fmaf((lane < 8) ? p0 : p1, hv, acc);
        den0 += p0; den1 += p1;
        asp = aspn; hv = hvn;
    }
    float den = (lane < 8) ? den0 : den1;
    float o = acc / (den + 1e-16f) + b1[lane];
    o = (o > 0.f) ? o : 0.f;                     // ReLU
    float v = o * W2[lane];                      // fused (16 -> 1) @W2
    v += __shfl_xor(v, 1, 64);
    v += __shfl_xor(v, 2, 64);
    v += __shfl_xor(v, 4, 64);
    v += __shfl_xor(v, 8, 64);
    if (lane == 0) h2out[d] = v;
}

// ---------------- layer-2 edge pass (CSR walk) ----------------
__global__ __launch_bounds__(256) void k_edge2(
        const int* __restrict__ offs, const int* __restrict__ csr,
        const float* __restrict__ h2,
        const float* __restrict__ a_src2, const float* __restrict__ a_dst2,
        const float* __restrict__ b2, float* __restrict__ out) {
    int t = threadIdx.x;
    int g = t >> 4, lane = t & 15;
    int d = blockIdx.x * 16 + g;
    if (d >= N_NODES) return;

    float as2 = a_src2[0], ad2 = a_dst2[0];
    float adv = h2[d] * ad2;
    int beg = offs[d], end = offs[d + 1];

    float den = 0.f, acc = 0.f;
    for (int e = beg + lane; e < end; e += 16) {
        float hs = h2[csr[e]];
        float a = fmaf(hs, as2, adv);
        a = (a > 0.f) ? a : 0.2f * a;
        float p = __expf(a);
        den += p;
        acc = fmaf(p, hs, acc);
    }
    #pragma unroll
    for (int m = 1; m < 16; m <<= 1) {
        den += __shfl_xor(den, m, 64);
        acc += __shfl_xor(acc, m, 64);
    }
    if (lane == 0) out[d] = acc / (den + 1e-16f) + b2[0];
}

// ---------------- launch ----------------
extern "C" void kernel_launch(void* const* d_in, const int* in_sizes, int n_in,
                              void* d_out, int out_size, void* d_ws, size_t ws_size,
                              hipStream_t stream) {
    const float* x      = (const float*)d_in[0];
    const int*   edge   = (const int*)  d_in[1];
    const float* W1     = (const float*)d_in[2];
    const float* a_src1 = (const float*)d_in[3];
    const float* a_dst1 = (const float*)d_in[4];
    const float* b1     = (const float*)d_in[5];
    const float* W2     = (const float*)d_in[6];
    const float* a_src2 = (const float*)d_in[7];
    const float* a_dst2 = (const float*)d_in[8];
    const float* b2     = (const float*)d_in[9];

    constexpr size_t A = 256;
    auto al = [](size_t b) { return (b + A - 1) / A * A; };
    char* ws = (char*)d_ws;
    size_t off = 0;
    int*      flag   = (int*)(ws + off);      off += al(256);
    int*      bcnt   = (int*)(ws + off);      off += al(NBUCK * 4);
    int*      bbase  = (int*)(ws + off);      off += al((NBUCK + 1) * 4);
    int*      bcur   = (int*)(ws + off);      off += al(NBUCK * 4);
    unsigned* staged = (unsigned*)(ws + off); off += al((size_t)E_TOT * 4);          // 26 MB
    int*      csr    = (int*)(ws + off);      off += al((size_t)E_TOT * 4);          // 26 MB
    int*      offs   = (int*)(ws + off);      off += al((size_t)(N_NODES + 1) * 4);
    __half*   h16    = (__half*)(ws + off);   off += al((size_t)N_NODES * NHID * 2); // 3.2 MB
    float*    asrc   = (float*)(ws + off);    off += al((size_t)N_NODES * 2 * 4);    // 0.8 MB
    float*    adst   = (float*)(ws + off);    off += al((size_t)N_NODES * 2 * 4);    // 0.8 MB
    float*    h2     = (float*)(ws + off);    off += al((size_t)N_NODES * 4);
    (void)ws_size; (void)in_sizes; (void)n_in; (void)out_size;

    hipMemsetAsync(bcnt, 0, NBUCK * 4, stream);

    k_detect<<<1, 64, 0, stream>>>(edge, flag);
    k_gemm1 <<<(N_NODES + 15) / 16, 256, 0, stream>>>(x, W1, a_src1, a_dst1, h16, asrc, adst);
    k_bcount<<<2048, 256, 0, stream>>>(edge, flag, bcnt);
    k_bscan <<<1, 256, 0, stream>>>(bcnt, bbase, bcur);
    k_bin   <<<NCHUNK, 256, 0, stream>>>(edge, flag, bcur, staged);
    k_sort  <<<NBUCK, 1024, 0, stream>>>(staged, bbase, csr, offs);
    k_edge1 <<<(N_NODES + 15) / 16, 256, 0, stream>>>(offs, csr, h16, asrc, adst, b1, W2, h2);
    k_edge2 <<<(N_NODES + 15) / 16, 256, 0, stream>>>(offs, csr, h2, a_src2, a_dst2, b2,
                                                      (float*)d_out);
}

// Round 5
// 307.979 us; speedup vs baseline: 3.9704x; 1.5463x over previous
//
#include <hip/hip_runtime.h>
#include <hip/hip_fp16.h>
#include <cstdint>
#include <cstddef>

#define N_NODES 100000
#define E_EDGES 6400000
#define E_TOT   (E_EDGES + N_NODES)
#define IN_CH   128
#define NHID    16              // HEADS*HID
#define BSHIFT  9               // 512 dsts per bucket
#define BSZ     512
#define NBUCK   196             // ceil(100000/512)
#define CHUNK   6144            // edges per k_bin block
#define BCAP    72              // LDS staging capacity per bucket (mean 31.5)
#define NCHUNK  ((E_TOT + CHUNK - 1) / CHUNK)   // 1058

// ---------------- detection: int64 vs int32 edge_index ----------------
__global__ void k_detect(const int* __restrict__ edge, int* __restrict__ flag) {
    if (blockIdx.x == 0 && threadIdx.x == 0) {
        int odd_or = 0;
        for (int i = 0; i < 64; i++) odd_or |= edge[2 * i + 1];
        flag[0] = (odd_or == 0) ? 1 : 0;   // 1 => data is int64 little-endian
    }
}

__device__ __forceinline__ int load_src(const int* e, size_t i, int m64) {
    return m64 ? e[2 * i] : e[i];
}
__device__ __forceinline__ int load_dst(const int* e, size_t i, int m64) {
    return m64 ? e[2 * ((size_t)E_EDGES + i)] : e[(size_t)E_EDGES + i];
}

// ------- layer-1 node features: h16 = fp16(x@W1), split alpha arrays --
__global__ __launch_bounds__(256) void k_gemm1(
        const float* __restrict__ x, const float* __restrict__ W1,
        const float* __restrict__ a_src1, const float* __restrict__ a_dst1,
        __half* __restrict__ h16, float* __restrict__ asrc,
        float* __restrict__ adst) {
    __shared__ __align__(16) float sW[IN_CH * NHID];   // 8 KB
    __shared__ __align__(16) float sx[16][132];        // padded stride
    __shared__ float sh[16][17];
    int t = threadIdx.x;
    int r = t >> 4, c = t & 15;
    int row = blockIdx.x * 16 + r;

    const float4* W4 = (const float4*)W1;
    ((float4*)sW)[t] = W4[t];
    ((float4*)sW)[t + 256] = W4[t + 256];

    if (row < N_NODES) {
        const float4* xr = (const float4*)(x + (size_t)row * IN_CH);
        float4 v0 = xr[c];
        float4 v1 = xr[c + 16];
        *(float4*)&sx[r][4 * c] = v0;
        *(float4*)&sx[r][64 + 4 * c] = v1;
    }
    __syncthreads();

    float acc = 0.f;
    if (row < N_NODES) {
        #pragma unroll 16
        for (int k = 0; k < IN_CH; k++) acc = fmaf(sx[r][k], sW[k * NHID + c], acc);
        h16[(size_t)row * NHID + c] = __float2half(acc);
    }
    sh[r][c] = acc;
    __syncthreads();

    if (row < N_NODES && c < 4) {
        int h = c & 1;
        const float* av = (c >= 2) ? a_dst1 : a_src1;
        float s = 0.f;
        #pragma unroll
        for (int q = 0; q < 8; q++) s = fmaf(sh[r][h * 8 + q], av[h * 8 + q], s);
        if (c < 2) asrc[2 * (size_t)row + c] = s;
        else       adst[2 * (size_t)row + (c - 2)] = s;
    }
}

// --- per-chunk 196-bucket histogram; coalesced row write, NO atomics --
__global__ __launch_bounds__(256) void k_ccount(const int* __restrict__ edge,
                                                const int* __restrict__ flag,
                                                int* __restrict__ ccnt) {
    __shared__ int sc[NBUCK];
    int m64 = flag[0];
    int t = threadIdx.x;
    for (int i = t; i < NBUCK; i += 256) sc[i] = 0;
    __syncthreads();
    size_t c0 = (size_t)blockIdx.x * CHUNK;
    size_t cend = c0 + CHUNK; if (cend > E_TOT) cend = E_TOT;
    for (size_t i = c0 + t; i < cend; i += 256) {
        int d = (i < E_EDGES) ? load_dst(edge, i, m64) : (int)(i - E_EDGES);
        atomicAdd(&sc[d >> BSHIFT], 1);
    }
    __syncthreads();
    for (int i = t; i < NBUCK; i += 256)
        ccnt[(size_t)blockIdx.x * NBUCK + i] = sc[i];
}

// --- per-bucket exclusive scan over chunks: exact per-chunk bases -----
__global__ __launch_bounds__(256) void k_cscan(int* __restrict__ ccnt,
                                               int* __restrict__ bcnt) {
    __shared__ int sd[256];
    __shared__ int carry;
    int b = blockIdx.x, t = threadIdx.x;
    if (t == 0) carry = 0;
    __syncthreads();
    for (int base = 0; base < NCHUNK; base += 256) {
        int c = base + t;
        int v = (c < NCHUNK) ? ccnt[(size_t)c * NBUCK + b] : 0;
        sd[t] = v;
        __syncthreads();
        for (int ofs = 1; ofs < 256; ofs <<= 1) {
            int a = sd[t];
            int bb = (t >= ofs) ? sd[t - ofs] : 0;
            __syncthreads();
            sd[t] = a + bb;
            __syncthreads();
        }
        if (c < NCHUNK) ccnt[(size_t)c * NBUCK + b] = sd[t] - v + carry;
        __syncthreads();
        if (t == 255) carry += sd[255];
        __syncthreads();
    }
    if (t == 0) bcnt[b] = carry;
}

// ---------------- tiny scan over 196 bucket totals ----------------
__global__ void k_bscan(const int* __restrict__ bcnt, int* __restrict__ bbase) {
    __shared__ int sd[256];
    int t = threadIdx.x;
    int v = (t < NBUCK) ? bcnt[t] : 0;
    sd[t] = v;
    __syncthreads();
    for (int ofs = 1; ofs < 256; ofs <<= 1) {
        int a = sd[t];
        int b = (t >= ofs) ? sd[t - ofs] : 0;
        __syncthreads();
        sd[t] = a + b;
        __syncthreads();
    }
    if (t < NBUCK) bbase[t] = sd[t] - v;        // exclusive
    if (t == NBUCK) bbase[NBUCK] = sd[NBUCK - 1];
}

// ------ binning with precomputed exact slots: ZERO global atomics -----
__global__ __launch_bounds__(256) void k_bin(const int* __restrict__ edge,
                                             const int* __restrict__ flag,
                                             const int* __restrict__ ccnt,
                                             const int* __restrict__ bbase,
                                             unsigned* __restrict__ staged) {
    __shared__ unsigned lbin[NBUCK][BCAP];   // 55 KB
    __shared__ int lcnt[NBUCK];
    __shared__ int lbase[NBUCK];
    int m64 = flag[0];
    int t = threadIdx.x;
    int g = t >> 4, lane = t & 15;

    size_t c0 = (size_t)blockIdx.x * CHUNK;
    if (c0 >= E_TOT) return;
    size_t cend = c0 + CHUNK; if (cend > E_TOT) cend = E_TOT;

    for (int i = t; i < NBUCK; i += 256) {
        lcnt[i] = 0;
        lbase[i] = bbase[i] + ccnt[(size_t)blockIdx.x * NBUCK + i];
    }
    __syncthreads();

    for (size_t i = c0 + t; i < cend; i += 256) {
        int s, d;
        if (i < E_EDGES) { s = load_src(edge, i, m64); d = load_dst(edge, i, m64); }
        else             { s = d = (int)(i - E_EDGES); }
        int b = d >> BSHIFT;
        unsigned v = (unsigned)s | ((unsigned)(d & (BSZ - 1)) << 17);
        int idx = atomicAdd(&lcnt[b], 1);
        if (idx < BCAP) lbin[b][idx] = v;
        else            staged[lbase[b] + idx] = v;   // exact slot, no atomic
    }
    __syncthreads();
    // cooperative coalesced flush of the LDS-staged majority
    for (int b = g; b < NBUCK; b += 16) {
        int n = min(lcnt[b], BCAP);
        if (!n) continue;
        int pos = lbase[b];
        for (int i = lane; i < n; i += 16) staged[pos + i] = lbin[b][i];
    }
}

// ------- per-bucket exact counting sort -> CSR (L2-local scatter) -----
__global__ __launch_bounds__(1024) void k_sort(const unsigned* __restrict__ staged,
                                               const int* __restrict__ bbase,
                                               int* __restrict__ csr,
                                               int* __restrict__ offs) {
    __shared__ int hist[BSZ];
    __shared__ int lcur[BSZ];
    int bkt = blockIdx.x;
    int t = threadIdx.x;
    int beg = bbase[bkt], end = bbase[bkt + 1];
    int dbase = bkt << BSHIFT;

    if (t < BSZ) hist[t] = 0;
    __syncthreads();
    for (int e = beg + t; e < end; e += 1024)
        atomicAdd(&hist[staged[e] >> 17], 1);
    __syncthreads();

    int myv = (t < BSZ) ? hist[t] : 0;
    __syncthreads();
    for (int ofs = 1; ofs < BSZ; ofs <<= 1) {
        int a = 0, b = 0;
        if (t < BSZ) { a = hist[t]; b = (t >= ofs) ? hist[t - ofs] : 0; }
        __syncthreads();
        if (t < BSZ) hist[t] = a + b;
        __syncthreads();
    }
    if (t < BSZ) {
        int excl = hist[t] - myv;
        lcur[t] = excl;
        int dd = dbase + t;
        if (dd < N_NODES) offs[dd] = beg + excl;
    }
    if (bkt == NBUCK - 1 && t == 0) offs[N_NODES] = E_TOT;
    __syncthreads();

    for (int e = beg + t; e < end; e += 1024) {
        unsigned v = staged[e];
        int pos = atomicAdd(&lcur[v >> 17], 1);
        csr[beg + pos] = (int)(v & 0x1FFFFu);   // 133 KB window: L2-resident
    }
}

// --- layer-1 edge pass: CSR walk, fused softmax + bias + ReLU + @W2 ---
__global__ __launch_bounds__(256) void k_edge1(
        const int* __restrict__ offs, const int* __restrict__ csr,
        const __half* __restrict__ h16, const float* __restrict__ asrc,
        const float* __restrict__ adst,
        const float* __restrict__ b1, const float* __restrict__ W2,
        float* __restrict__ h2out) {
    int t = threadIdx.x;
    int g = t >> 4, lane = t & 15;
    int d = blockIdx.x * 16 + g;
    if (d >= N_NODES) return;

    float2 adp = ((const float2*)adst)[d];
    int beg = offs[d], end = offs[d + 1];

    float acc = 0.f, den0 = 0.f, den1 = 0.f;
    int s = csr[beg];
    float2 asp = ((const float2*)asrc)[s];
    float hv = __half2float(h16[(size_t)s * NHID + lane]);
    for (int e = beg; e < end; e++) {
        int sn = (e + 1 < end) ? csr[e + 1] : 0;
        float2 aspn = ((const float2*)asrc)[sn];
        float hvn = __half2float(h16[(size_t)sn * NHID + lane]);
        float a0 = asp.x + adp.x; a0 = (a0 > 0.f) ? a0 : 0.2f * a0;
        float a1 = asp.y + adp.y; a1 = (a1 > 0.f) ? a1 : 0.2f * a1;
        float p0 = __expf(a0), p1 = __expf(a1);
        acc = fmaf((lane < 8) ? p0 : p1, hv, acc);
        den0 += p0; den1 += p1;
        asp = aspn; hv = hvn;
    }
    float den = (lane < 8) ? den0 : den1;
    float o = acc / (den + 1e-16f) + b1[lane];
    o = (o > 0.f) ? o : 0.f;                     // ReLU
    float v = o * W2[lane];                      // fused (16 -> 1) @W2
    v += __shfl_xor(v, 1, 64);
    v += __shfl_xor(v, 2, 64);
    v += __shfl_xor(v, 4, 64);
    v += __shfl_xor(v, 8, 64);
    if (lane == 0) h2out[d] = v;
}

// ---------------- layer-2 edge pass (CSR walk) ----------------
__global__ __launch_bounds__(256) void k_edge2(
        const int* __restrict__ offs, const int* __restrict__ csr,
        const float* __restrict__ h2,
        const float* __restrict__ a_src2, const float* __restrict__ a_dst2,
        const float* __restrict__ b2, float* __restrict__ out) {
    int t = threadIdx.x;
    int g = t >> 4, lane = t & 15;
    int d = blockIdx.x * 16 + g;
    if (d >= N_NODES) return;

    float as2 = a_src2[0], ad2 = a_dst2[0];
    float adv = h2[d] * ad2;
    int beg = offs[d], end = offs[d + 1];

    float den = 0.f, acc = 0.f;
    for (int e = beg + lane; e < end; e += 16) {
        float hs = h2[csr[e]];
        float a = fmaf(hs, as2, adv);
        a = (a > 0.f) ? a : 0.2f * a;
        float p = __expf(a);
        den += p;
        acc = fmaf(p, hs, acc);
    }
    #pragma unroll
    for (int m = 1; m < 16; m <<= 1) {
        den += __shfl_xor(den, m, 64);
        acc += __shfl_xor(acc, m, 64);
    }
    if (lane == 0) out[d] = acc / (den + 1e-16f) + b2[0];
}

// ---------------- launch ----------------
extern "C" void kernel_launch(void* const* d_in, const int* in_sizes, int n_in,
                              void* d_out, int out_size, void* d_ws, size_t ws_size,
                              hipStream_t stream) {
    const float* x      = (const float*)d_in[0];
    const int*   edge   = (const int*)  d_in[1];
    const float* W1     = (const float*)d_in[2];
    const float* a_src1 = (const float*)d_in[3];
    const float* a_dst1 = (const float*)d_in[4];
    const float* b1     = (const float*)d_in[5];
    const float* W2     = (const float*)d_in[6];
    const float* a_src2 = (const float*)d_in[7];
    const float* a_dst2 = (const float*)d_in[8];
    const float* b2     = (const float*)d_in[9];

    constexpr size_t A = 256;
    auto al = [](size_t b) { return (b + A - 1) / A * A; };
    char* ws = (char*)d_ws;
    size_t off = 0;
    int*      flag   = (int*)(ws + off);      off += al(256);
    int*      ccnt   = (int*)(ws + off);      off += al((size_t)NCHUNK * NBUCK * 4); // 830 KB
    int*      bcnt   = (int*)(ws + off);      off += al(NBUCK * 4);
    int*      bbase  = (int*)(ws + off);      off += al((NBUCK + 1) * 4);
    unsigned* staged = (unsigned*)(ws + off); off += al((size_t)E_TOT * 4);          // 26 MB
    int*      csr    = (int*)(ws + off);      off += al((size_t)E_TOT * 4);          // 26 MB
    int*      offs   = (int*)(ws + off);      off += al((size_t)(N_NODES + 1) * 4);
    __half*   h16    = (__half*)(ws + off);   off += al((size_t)N_NODES * NHID * 2); // 3.2 MB
    float*    asrc   = (float*)(ws + off);    off += al((size_t)N_NODES * 2 * 4);    // 0.8 MB
    float*    adst   = (float*)(ws + off);    off += al((size_t)N_NODES * 2 * 4);    // 0.8 MB
    float*    h2     = (float*)(ws + off);    off += al((size_t)N_NODES * 4);
    (void)ws_size; (void)in_sizes; (void)n_in; (void)out_size;

    k_detect<<<1, 64, 0, stream>>>(edge, flag);
    k_gemm1 <<<(N_NODES + 15) / 16, 256, 0, stream>>>(x, W1, a_src1, a_dst1, h16, asrc, adst);
    k_ccount<<<NCHUNK, 256, 0, stream>>>(edge, flag, ccnt);
    k_cscan <<<NBUCK, 256, 0, stream>>>(ccnt, bcnt);
    k_bscan <<<1, 256, 0, stream>>>(bcnt, bbase);
    k_bin   <<<NCHUNK, 256, 0, stream>>>(edge, flag, ccnt, bbase, staged);
    k_sort  <<<NBUCK, 1024, 0, stream>>>(staged, bbase, csr, offs);
    k_edge1 <<<(N_NODES + 15) / 16, 256, 0, stream>>>(offs, csr, h16, asrc, adst, b1, W2, h2);
    k_edge2 <<<(N_NODES + 15) / 16, 256, 0, stream>>>(offs, csr, h2, a_src2, a_dst2, b2,
                                                      (float*)d_out);
}

// Round 6
// 294.087 us; speedup vs baseline: 4.1579x; 1.0472x over previous
//
#include <hip/hip_runtime.h>
#include <hip/hip_fp16.h>
#include <cstdint>
#include <cstddef>

#define N_NODES 100000
#define E_EDGES 6400000
#define E_TOT   (E_EDGES + N_NODES)
#define IN_CH   128
#define NHID    16              // HEADS*HID
#define BSHIFT  9               // 512 dsts per bucket
#define BSZ     512
#define NBUCK   196             // ceil(100000/512)
#define CHUNK   6144            // edges per k_bin block
#define BCAP    72              // LDS staging capacity per bucket (mean 31.5)
#define NCHUNK  ((E_TOT + CHUNK - 1) / CHUNK)   // 1058

// ---------------- detection: int64 vs int32 edge_index ----------------
__global__ void k_detect(const int* __restrict__ edge, int* __restrict__ flag) {
    if (blockIdx.x == 0 && threadIdx.x == 0) {
        int odd_or = 0;
        for (int i = 0; i < 64; i++) odd_or |= edge[2 * i + 1];
        flag[0] = (odd_or == 0) ? 1 : 0;   // 1 => data is int64 little-endian
    }
}

__device__ __forceinline__ int load_src(const int* e, size_t i, int m64) {
    return m64 ? e[2 * i] : e[i];
}
__device__ __forceinline__ int load_dst(const int* e, size_t i, int m64) {
    return m64 ? e[2 * ((size_t)E_EDGES + i)] : e[(size_t)E_EDGES + i];
}

// ------- layer-1 node features: h16 = fp16(x@W1), split alpha arrays --
__global__ __launch_bounds__(256) void k_gemm1(
        const float* __restrict__ x, const float* __restrict__ W1,
        const float* __restrict__ a_src1, const float* __restrict__ a_dst1,
        __half* __restrict__ h16, float* __restrict__ asrc,
        float* __restrict__ adst) {
    __shared__ __align__(16) float sW[IN_CH * NHID];   // 8 KB
    __shared__ __align__(16) float sx[16][132];        // padded stride
    __shared__ float sh[16][17];
    int t = threadIdx.x;
    int r = t >> 4, c = t & 15;
    int row = blockIdx.x * 16 + r;

    const float4* W4 = (const float4*)W1;
    ((float4*)sW)[t] = W4[t];
    ((float4*)sW)[t + 256] = W4[t + 256];

    if (row < N_NODES) {
        const float4* xr = (const float4*)(x + (size_t)row * IN_CH);
        float4 v0 = xr[c];
        float4 v1 = xr[c + 16];
        *(float4*)&sx[r][4 * c] = v0;
        *(float4*)&sx[r][64 + 4 * c] = v1;
    }
    __syncthreads();

    float acc = 0.f;
    if (row < N_NODES) {
        #pragma unroll 16
        for (int k = 0; k < IN_CH; k++) acc = fmaf(sx[r][k], sW[k * NHID + c], acc);
        h16[(size_t)row * NHID + c] = __float2half(acc);
    }
    sh[r][c] = acc;
    __syncthreads();

    if (row < N_NODES && c < 4) {
        int h = c & 1;
        const float* av = (c >= 2) ? a_dst1 : a_src1;
        float s = 0.f;
        #pragma unroll
        for (int q = 0; q < 8; q++) s = fmaf(sh[r][h * 8 + q], av[h * 8 + q], s);
        if (c < 2) asrc[2 * (size_t)row + c] = s;
        else       adst[2 * (size_t)row + (c - 2)] = s;
    }
}

// --- per-chunk 196-bucket histogram; coalesced row write, NO atomics --
__global__ __launch_bounds__(256) void k_ccount(const int* __restrict__ edge,
                                                const int* __restrict__ flag,
                                                int* __restrict__ ccnt) {
    __shared__ int sc[NBUCK];
    int m64 = flag[0];
    int t = threadIdx.x;
    for (int i = t; i < NBUCK; i += 256) sc[i] = 0;
    __syncthreads();
    size_t c0 = (size_t)blockIdx.x * CHUNK;
    size_t cend = c0 + CHUNK; if (cend > E_TOT) cend = E_TOT;
    for (size_t i = c0 + t; i < cend; i += 256) {
        int d = (i < E_EDGES) ? load_dst(edge, i, m64) : (int)(i - E_EDGES);
        atomicAdd(&sc[d >> BSHIFT], 1);
    }
    __syncthreads();
    for (int i = t; i < NBUCK; i += 256)
        ccnt[(size_t)blockIdx.x * NBUCK + i] = sc[i];
}

// --- per-bucket exclusive scan over chunks: exact per-chunk bases -----
__global__ __launch_bounds__(256) void k_cscan(int* __restrict__ ccnt,
                                               int* __restrict__ bcnt) {
    __shared__ int sd[256];
    __shared__ int carry;
    int b = blockIdx.x, t = threadIdx.x;
    if (t == 0) carry = 0;
    __syncthreads();
    for (int base = 0; base < NCHUNK; base += 256) {
        int c = base + t;
        int v = (c < NCHUNK) ? ccnt[(size_t)c * NBUCK + b] : 0;
        sd[t] = v;
        __syncthreads();
        for (int ofs = 1; ofs < 256; ofs <<= 1) {
            int a = sd[t];
            int bb = (t >= ofs) ? sd[t - ofs] : 0;
            __syncthreads();
            sd[t] = a + bb;
            __syncthreads();
        }
        if (c < NCHUNK) ccnt[(size_t)c * NBUCK + b] = sd[t] - v + carry;
        __syncthreads();
        if (t == 255) carry += sd[255];
        __syncthreads();
    }
    if (t == 0) bcnt[b] = carry;
}

// ---------------- tiny scan over 196 bucket totals ----------------
__global__ void k_bscan(const int* __restrict__ bcnt, int* __restrict__ bbase) {
    __shared__ int sd[256];
    int t = threadIdx.x;
    int v = (t < NBUCK) ? bcnt[t] : 0;
    sd[t] = v;
    __syncthreads();
    for (int ofs = 1; ofs < 256; ofs <<= 1) {
        int a = sd[t];
        int b = (t >= ofs) ? sd[t - ofs] : 0;
        __syncthreads();
        sd[t] = a + b;
        __syncthreads();
    }
    if (t < NBUCK) bbase[t] = sd[t] - v;        // exclusive
    if (t == NBUCK) bbase[NBUCK] = sd[NBUCK - 1];
}

// ------ binning with precomputed exact slots: ZERO global atomics -----
__global__ __launch_bounds__(256) void k_bin(const int* __restrict__ edge,
                                             const int* __restrict__ flag,
                                             const int* __restrict__ ccnt,
                                             const int* __restrict__ bbase,
                                             unsigned* __restrict__ staged) {
    __shared__ unsigned lbin[NBUCK][BCAP];   // 55 KB
    __shared__ int lcnt[NBUCK];
    __shared__ int lbase[NBUCK];
    int m64 = flag[0];
    int t = threadIdx.x;
    int g = t >> 4, lane = t & 15;

    size_t c0 = (size_t)blockIdx.x * CHUNK;
    if (c0 >= E_TOT) return;
    size_t cend = c0 + CHUNK; if (cend > E_TOT) cend = E_TOT;

    for (int i = t; i < NBUCK; i += 256) {
        lcnt[i] = 0;
        lbase[i] = bbase[i] + ccnt[(size_t)blockIdx.x * NBUCK + i];
    }
    __syncthreads();

    for (size_t i = c0 + t; i < cend; i += 256) {
        int s, d;
        if (i < E_EDGES) { s = load_src(edge, i, m64); d = load_dst(edge, i, m64); }
        else             { s = d = (int)(i - E_EDGES); }
        int b = d >> BSHIFT;
        unsigned v = (unsigned)s | ((unsigned)(d & (BSZ - 1)) << 17);
        int idx = atomicAdd(&lcnt[b], 1);
        if (idx < BCAP) lbin[b][idx] = v;
        else            staged[lbase[b] + idx] = v;   // exact slot, no atomic
    }
    __syncthreads();
    // cooperative coalesced flush of the LDS-staged majority
    for (int b = g; b < NBUCK; b += 16) {
        int n = min(lcnt[b], BCAP);
        if (!n) continue;
        int pos = lbase[b];
        for (int i = lane; i < n; i += 16) staged[pos + i] = lbin[b][i];
    }
}

// ------- per-bucket exact counting sort -> CSR (L2-local scatter) -----
__global__ __launch_bounds__(1024) void k_sort(const unsigned* __restrict__ staged,
                                               const int* __restrict__ bbase,
                                               int* __restrict__ csr,
                                               int* __restrict__ offs) {
    __shared__ int hist[BSZ];
    __shared__ int lcur[BSZ];
    int bkt = blockIdx.x;
    int t = threadIdx.x;
    int beg = bbase[bkt], end = bbase[bkt + 1];
    int dbase = bkt << BSHIFT;

    if (t < BSZ) hist[t] = 0;
    __syncthreads();
    for (int e = beg + t; e < end; e += 1024)
        atomicAdd(&hist[staged[e] >> 17], 1);
    __syncthreads();

    int myv = (t < BSZ) ? hist[t] : 0;
    __syncthreads();
    for (int ofs = 1; ofs < BSZ; ofs <<= 1) {
        int a = 0, b = 0;
        if (t < BSZ) { a = hist[t]; b = (t >= ofs) ? hist[t - ofs] : 0; }
        __syncthreads();
        if (t < BSZ) hist[t] = a + b;
        __syncthreads();
    }
    if (t < BSZ) {
        int excl = hist[t] - myv;
        lcur[t] = excl;
        int dd = dbase + t;
        if (dd < N_NODES) offs[dd] = beg + excl;
    }
    if (bkt == NBUCK - 1 && t == 0) offs[N_NODES] = E_TOT;
    __syncthreads();

    for (int e = beg + t; e < end; e += 1024) {
        unsigned v = staged[e];
        int pos = atomicAdd(&lcur[v >> 17], 1);
        csr[beg + pos] = (int)(v & 0x1FFFFu);   // 133 KB window: L2-resident
    }
}

// --- layer-1 edge pass: two-phase batch (lane=edge, then lane=channel)
// Phase A: 16 lanes each handle one edge of the batch (one exp pair per
// edge, not 16x redundant). Phase B: broadcast (s,p0,p1) from lane k via
// group-local shfl; 16 lanes do the coalesced 32B h16 row fma.
__global__ __launch_bounds__(256) void k_edge1(
        const int* __restrict__ offs, const int* __restrict__ csr,
        const __half* __restrict__ h16, const float* __restrict__ asrc,
        const float* __restrict__ adst,
        const float* __restrict__ b1, const float* __restrict__ W2,
        float* __restrict__ h2out) {
    int t = threadIdx.x;
    int lane = t & 15;
    int gw = t & 0x30;               // group base within the 64-lane wave
    int d = blockIdx.x * 16 + (t >> 4);
    if (d >= N_NODES) return;

    float2 adp = ((const float2*)adst)[d];
    int beg = offs[d], end = offs[d + 1];

    float acc = 0.f, den0 = 0.f, den1 = 0.f;
    for (int e0 = beg; e0 < end; e0 += 16) {
        int rem = end - e0; if (rem > 16) rem = 16;
        // ---- phase A: lane = edge ----
        int idx = e0 + lane;
        int s = 0;
        float p0 = 0.f, p1 = 0.f;
        if (lane < rem) {
            s = csr[idx];
            float2 asp = ((const float2*)asrc)[s];
            float a0 = asp.x + adp.x; a0 = (a0 > 0.f) ? a0 : 0.2f * a0;
            float a1 = asp.y + adp.y; a1 = (a1 > 0.f) ? a1 : 0.2f * a1;
            p0 = __expf(a0); p1 = __expf(a1);
            den0 += p0; den1 += p1;
        }
        // ---- phase B: lane = channel ----
        for (int k = 0; k < rem; k++) {
            int srcl = gw + k;
            int   sk = __shfl(s,  srcl, 64);
            float q0 = __shfl(p0, srcl, 64);
            float q1 = __shfl(p1, srcl, 64);
            float pk = (lane < 8) ? q0 : q1;
            float hv = __half2float(h16[(size_t)sk * NHID + lane]);
            acc = fmaf(pk, hv, acc);
        }
    }
    // reduce den partials across the 16 lanes of the group
    #pragma unroll
    for (int m = 1; m < 16; m <<= 1) {
        den0 += __shfl_xor(den0, m, 64);
        den1 += __shfl_xor(den1, m, 64);
    }
    float den = (lane < 8) ? den0 : den1;
    float o = acc / (den + 1e-16f) + b1[lane];
    o = (o > 0.f) ? o : 0.f;                     // ReLU
    float v = o * W2[lane];                      // fused (16 -> 1) @W2
    v += __shfl_xor(v, 1, 64);
    v += __shfl_xor(v, 2, 64);
    v += __shfl_xor(v, 4, 64);
    v += __shfl_xor(v, 8, 64);
    if (lane == 0) h2out[d] = v;
}

// ---------------- layer-2 edge pass (CSR walk) ----------------
__global__ __launch_bounds__(256) void k_edge2(
        const int* __restrict__ offs, const int* __restrict__ csr,
        const float* __restrict__ h2,
        const float* __restrict__ a_src2, const float* __restrict__ a_dst2,
        const float* __restrict__ b2, float* __restrict__ out) {
    int t = threadIdx.x;
    int g = t >> 4, lane = t & 15;
    int d = blockIdx.x * 16 + g;
    if (d >= N_NODES) return;

    float as2 = a_src2[0], ad2 = a_dst2[0];
    float adv = h2[d] * ad2;
    int beg = offs[d], end = offs[d + 1];

    float den = 0.f, acc = 0.f;
    for (int e = beg + lane; e < end; e += 16) {
        float hs = h2[csr[e]];
        float a = fmaf(hs, as2, adv);
        a = (a > 0.f) ? a : 0.2f * a;
        float p = __expf(a);
        den += p;
        acc = fmaf(p, hs, acc);
    }
    #pragma unroll
    for (int m = 1; m < 16; m <<= 1) {
        den += __shfl_xor(den, m, 64);
        acc += __shfl_xor(acc, m, 64);
    }
    if (lane == 0) out[d] = acc / (den + 1e-16f) + b2[0];
}

// ---------------- launch ----------------
extern "C" void kernel_launch(void* const* d_in, const int* in_sizes, int n_in,
                              void* d_out, int out_size, void* d_ws, size_t ws_size,
                              hipStream_t stream) {
    const float* x      = (const float*)d_in[0];
    const int*   edge   = (const int*)  d_in[1];
    const float* W1     = (const float*)d_in[2];
    const float* a_src1 = (const float*)d_in[3];
    const float* a_dst1 = (const float*)d_in[4];
    const float* b1     = (const float*)d_in[5];
    const float* W2     = (const float*)d_in[6];
    const float* a_src2 = (const float*)d_in[7];
    const float* a_dst2 = (const float*)d_in[8];
    const float* b2     = (const float*)d_in[9];

    constexpr size_t A = 256;
    auto al = [](size_t b) { return (b + A - 1) / A * A; };
    char* ws = (char*)d_ws;
    size_t off = 0;
    int*      flag   = (int*)(ws + off);      off += al(256);
    int*      ccnt   = (int*)(ws + off);      off += al((size_t)NCHUNK * NBUCK * 4); // 830 KB
    int*      bcnt   = (int*)(ws + off);      off += al(NBUCK * 4);
    int*      bbase  = (int*)(ws + off);      off += al((NBUCK + 1) * 4);
    unsigned* staged = (unsigned*)(ws + off); off += al((size_t)E_TOT * 4);          // 26 MB
    int*      csr    = (int*)(ws + off);      off += al((size_t)E_TOT * 4);          // 26 MB
    int*      offs   = (int*)(ws + off);      off += al((size_t)(N_NODES + 1) * 4);
    __half*   h16    = (__half*)(ws + off);   off += al((size_t)N_NODES * NHID * 2); // 3.2 MB
    float*    asrc   = (float*)(ws + off);    off += al((size_t)N_NODES * 2 * 4);    // 0.8 MB
    float*    adst   = (float*)(ws + off);    off += al((size_t)N_NODES * 2 * 4);    // 0.8 MB
    float*    h2     = (float*)(ws + off);    off += al((size_t)N_NODES * 4);
    (void)ws_size; (void)in_sizes; (void)n_in; (void)out_size;

    k_detect<<<1, 64, 0, stream>>>(edge, flag);
    k_gemm1 <<<(N_NODES + 15) / 16, 256, 0, stream>>>(x, W1, a_src1, a_dst1, h16, asrc, adst);
    k_ccount<<<NCHUNK, 256, 0, stream>>>(edge, flag, ccnt);
    k_cscan <<<NBUCK, 256, 0, stream>>>(ccnt, bcnt);
    k_bscan <<<1, 256, 0, stream>>>(bcnt, bbase);
    k_bin   <<<NCHUNK, 256, 0, stream>>>(edge, flag, ccnt, bbase, staged);
    k_sort  <<<NBUCK, 1024, 0, stream>>>(staged, bbase, csr, offs);
    k_edge1 <<<(N_NODES + 15) / 16, 256, 0, stream>>>(offs, csr, h16, asrc, adst, b1, W2, h2);
    k_edge2 <<<(N_NODES + 15) / 16, 256, 0, stream>>>(offs, csr, h2, a_src2, a_dst2, b2,
                                                      (float*)d_out);
}

// Round 7
// 263.619 us; speedup vs baseline: 4.6385x; 1.1156x over previous
//
#include <hip/hip_runtime.h>
#include <hip/hip_fp16.h>
#include <cstdint>
#include <cstddef>

#define N_NODES 100000
#define E_EDGES 6400000
#define E_TOT   (E_EDGES + N_NODES)
#define IN_CH   128
#define NHID    16              // HEADS*HID
#define BSHIFT  9               // 512 dsts per bucket
#define BSZ     512
#define NBUCK   196             // ceil(100000/512)
#define CHUNK   6144            // edges per k_bin block
#define BCAP    72              // LDS staging capacity per bucket (mean 31.5)
#define NCHUNK  ((E_TOT + CHUNK - 1) / CHUNK)   // 1058

// ---------------- detection: int64 vs int32 edge_index ----------------
__global__ void k_detect(const int* __restrict__ edge, int* __restrict__ flag) {
    if (blockIdx.x == 0 && threadIdx.x == 0) {
        int odd_or = 0;
        for (int i = 0; i < 64; i++) odd_or |= edge[2 * i + 1];
        flag[0] = (odd_or == 0) ? 1 : 0;   // 1 => data is int64 little-endian
    }
}

__device__ __forceinline__ int load_src(const int* e, size_t i, int m64) {
    return m64 ? e[2 * i] : e[i];
}
__device__ __forceinline__ int load_dst(const int* e, size_t i, int m64) {
    return m64 ? e[2 * ((size_t)E_EDGES + i)] : e[(size_t)E_EDGES + i];
}

// ------- layer-1 node features: h16 = fp16(x@W1), split alpha arrays --
__global__ __launch_bounds__(256) void k_gemm1(
        const float* __restrict__ x, const float* __restrict__ W1,
        const float* __restrict__ a_src1, const float* __restrict__ a_dst1,
        __half* __restrict__ h16, float* __restrict__ asrc,
        float* __restrict__ adst) {
    __shared__ __align__(16) float sW[IN_CH * NHID];   // 8 KB
    __shared__ __align__(16) float sx[16][132];        // padded stride
    __shared__ float sh[16][17];
    int t = threadIdx.x;
    int r = t >> 4, c = t & 15;
    int row = blockIdx.x * 16 + r;

    const float4* W4 = (const float4*)W1;
    ((float4*)sW)[t] = W4[t];
    ((float4*)sW)[t + 256] = W4[t + 256];

    if (row < N_NODES) {
        const float4* xr = (const float4*)(x + (size_t)row * IN_CH);
        float4 v0 = xr[c];
        float4 v1 = xr[c + 16];
        *(float4*)&sx[r][4 * c] = v0;
        *(float4*)&sx[r][64 + 4 * c] = v1;
    }
    __syncthreads();

    float acc = 0.f;
    if (row < N_NODES) {
        #pragma unroll 16
        for (int k = 0; k < IN_CH; k++) acc = fmaf(sx[r][k], sW[k * NHID + c], acc);
        h16[(size_t)row * NHID + c] = __float2half(acc);
    }
    sh[r][c] = acc;
    __syncthreads();

    if (row < N_NODES && c < 4) {
        int h = c & 1;
        const float* av = (c >= 2) ? a_dst1 : a_src1;
        float s = 0.f;
        #pragma unroll
        for (int q = 0; q < 8; q++) s = fmaf(sh[r][h * 8 + q], av[h * 8 + q], s);
        if (c < 2) asrc[2 * (size_t)row + c] = s;
        else       adst[2 * (size_t)row + (c - 2)] = s;
    }
}

// --- per-chunk 196-bucket histogram; coalesced row write, NO atomics --
__global__ __launch_bounds__(256) void k_ccount(const int* __restrict__ edge,
                                                const int* __restrict__ flag,
                                                int* __restrict__ ccnt) {
    __shared__ int sc[NBUCK];
    int m64 = flag[0];
    int t = threadIdx.x;
    for (int i = t; i < NBUCK; i += 256) sc[i] = 0;
    __syncthreads();
    size_t c0 = (size_t)blockIdx.x * CHUNK;
    size_t cend = c0 + CHUNK; if (cend > E_TOT) cend = E_TOT;
    for (size_t i = c0 + t; i < cend; i += 256) {
        int d = (i < E_EDGES) ? load_dst(edge, i, m64) : (int)(i - E_EDGES);
        atomicAdd(&sc[d >> BSHIFT], 1);
    }
    __syncthreads();
    for (int i = t; i < NBUCK; i += 256)
        ccnt[(size_t)blockIdx.x * NBUCK + i] = sc[i];
}

// --- per-bucket exclusive scan over chunks: exact per-chunk bases -----
__global__ __launch_bounds__(256) void k_cscan(int* __restrict__ ccnt,
                                               int* __restrict__ bcnt) {
    __shared__ int sd[256];
    __shared__ int carry;
    int b = blockIdx.x, t = threadIdx.x;
    if (t == 0) carry = 0;
    __syncthreads();
    for (int base = 0; base < NCHUNK; base += 256) {
        int c = base + t;
        int v = (c < NCHUNK) ? ccnt[(size_t)c * NBUCK + b] : 0;
        sd[t] = v;
        __syncthreads();
        for (int ofs = 1; ofs < 256; ofs <<= 1) {
            int a = sd[t];
            int bb = (t >= ofs) ? sd[t - ofs] : 0;
            __syncthreads();
            sd[t] = a + bb;
            __syncthreads();
        }
        if (c < NCHUNK) ccnt[(size_t)c * NBUCK + b] = sd[t] - v + carry;
        __syncthreads();
        if (t == 255) carry += sd[255];
        __syncthreads();
    }
    if (t == 0) bcnt[b] = carry;
}

// ---------------- tiny scan over 196 bucket totals ----------------
__global__ void k_bscan(const int* __restrict__ bcnt, int* __restrict__ bbase) {
    __shared__ int sd[256];
    int t = threadIdx.x;
    int v = (t < NBUCK) ? bcnt[t] : 0;
    sd[t] = v;
    __syncthreads();
    for (int ofs = 1; ofs < 256; ofs <<= 1) {
        int a = sd[t];
        int b = (t >= ofs) ? sd[t - ofs] : 0;
        __syncthreads();
        sd[t] = a + b;
        __syncthreads();
    }
    if (t < NBUCK) bbase[t] = sd[t] - v;        // exclusive
    if (t == NBUCK) bbase[NBUCK] = sd[NBUCK - 1];
}

// ------ binning with precomputed exact slots: ZERO global atomics -----
__global__ __launch_bounds__(256) void k_bin(const int* __restrict__ edge,
                                             const int* __restrict__ flag,
                                             const int* __restrict__ ccnt,
                                             const int* __restrict__ bbase,
                                             unsigned* __restrict__ staged) {
    __shared__ unsigned lbin[NBUCK][BCAP];   // 55 KB
    __shared__ int lcnt[NBUCK];
    __shared__ int lbase[NBUCK];
    int m64 = flag[0];
    int t = threadIdx.x;
    int g = t >> 4, lane = t & 15;

    size_t c0 = (size_t)blockIdx.x * CHUNK;
    if (c0 >= E_TOT) return;
    size_t cend = c0 + CHUNK; if (cend > E_TOT) cend = E_TOT;

    for (int i = t; i < NBUCK; i += 256) {
        lcnt[i] = 0;
        lbase[i] = bbase[i] + ccnt[(size_t)blockIdx.x * NBUCK + i];
    }
    __syncthreads();

    for (size_t i = c0 + t; i < cend; i += 256) {
        int s, d;
        if (i < E_EDGES) { s = load_src(edge, i, m64); d = load_dst(edge, i, m64); }
        else             { s = d = (int)(i - E_EDGES); }
        int b = d >> BSHIFT;
        unsigned v = (unsigned)s | ((unsigned)(d & (BSZ - 1)) << 17);
        int idx = atomicAdd(&lcnt[b], 1);
        if (idx < BCAP) lbin[b][idx] = v;
        else            staged[lbase[b] + idx] = v;   // exact slot, no atomic
    }
    __syncthreads();
    // cooperative coalesced flush of the LDS-staged majority
    for (int b = g; b < NBUCK; b += 16) {
        int n = min(lcnt[b], BCAP);
        if (!n) continue;
        int pos = lbase[b];
        for (int i = lane; i < n; i += 16) staged[pos + i] = lbin[b][i];
    }
}

// ------- per-bucket exact counting sort -> CSR (L2-local scatter) -----
__global__ __launch_bounds__(1024) void k_sort(const unsigned* __restrict__ staged,
                                               const int* __restrict__ bbase,
                                               int* __restrict__ csr,
                                               int* __restrict__ offs) {
    __shared__ int hist[BSZ];
    __shared__ int lcur[BSZ];
    int bkt = blockIdx.x;
    int t = threadIdx.x;
    int beg = bbase[bkt], end = bbase[bkt + 1];
    int dbase = bkt << BSHIFT;

    if (t < BSZ) hist[t] = 0;
    __syncthreads();
    for (int e = beg + t; e < end; e += 1024)
        atomicAdd(&hist[staged[e] >> 17], 1);
    __syncthreads();

    int myv = (t < BSZ) ? hist[t] : 0;
    __syncthreads();
    for (int ofs = 1; ofs < BSZ; ofs <<= 1) {
        int a = 0, b = 0;
        if (t < BSZ) { a = hist[t]; b = (t >= ofs) ? hist[t - ofs] : 0; }
        __syncthreads();
        if (t < BSZ) hist[t] = a + b;
        __syncthreads();
    }
    if (t < BSZ) {
        int excl = hist[t] - myv;
        lcur[t] = excl;
        int dd = dbase + t;
        if (dd < N_NODES) offs[dd] = beg + excl;
    }
    if (bkt == NBUCK - 1 && t == 0) offs[N_NODES] = E_TOT;
    __syncthreads();

    for (int e = beg + t; e < end; e += 1024) {
        unsigned v = staged[e];
        int pos = atomicAdd(&lcur[v >> 17], 1);
        csr[beg + pos] = (int)(v & 0x1FFFFu);   // 133 KB window: L2-resident
    }
}

// --- layer-1 edge pass: lane=edge, full 32B h16 row per lane ----------
// Each lane owns one edge end-to-end (own exp pair, own float4x2 row
// load, acc[16] in registers) -> no inner-loop shuffles, no broadcast
// dependence; distance-1 prefetch keeps gathers in flight. Final 16x16
// transpose-reduce via padded LDS (2-way bank aliasing = free).
__global__ __launch_bounds__(256) void k_edge1(
        const int* __restrict__ offs, const int* __restrict__ csr,
        const __half* __restrict__ h16, const float* __restrict__ asrc,
        const float* __restrict__ adst,
        const float* __restrict__ b1, const float* __restrict__ W2,
        float* __restrict__ h2out) {
    __shared__ float sacc[256][17];   // 17.4 KB, padded
    int t = threadIdx.x;
    int lane = t & 15;
    int g = t >> 4;
    int d = blockIdx.x * 16 + g;
    if (d >= N_NODES) return;

    float2 adp = ((const float2*)adst)[d];
    int beg = offs[d], end = offs[d + 1];

    float acc[16];
    #pragma unroll
    for (int c = 0; c < 16; c++) acc[c] = 0.f;
    float den0 = 0.f, den1 = 0.f;

    int e = beg + lane;
    int s = 0; float2 asp = make_float2(0.f, 0.f);
    float4 r0 = make_float4(0.f, 0.f, 0.f, 0.f), r1 = r0;
    if (e < end) {
        s = csr[e];
        asp = ((const float2*)asrc)[s];
        const float4* hp = (const float4*)(h16 + (size_t)s * NHID);
        r0 = hp[0]; r1 = hp[1];
    }
    while (e < end) {
        // prefetch next edge before consuming current
        int en = e + 16;
        int sn = 0; float2 aspn = make_float2(0.f, 0.f);
        float4 rn0 = make_float4(0.f, 0.f, 0.f, 0.f), rn1 = rn0;
        if (en < end) {
            sn = csr[en];
            aspn = ((const float2*)asrc)[sn];
            const float4* hp = (const float4*)(h16 + (size_t)sn * NHID);
            rn0 = hp[0]; rn1 = hp[1];
        }
        float a0 = asp.x + adp.x; a0 = (a0 > 0.f) ? a0 : 0.2f * a0;
        float a1 = asp.y + adp.y; a1 = (a1 > 0.f) ? a1 : 0.2f * a1;
        float p0 = __expf(a0), p1 = __expf(a1);
        den0 += p0; den1 += p1;
        const __half2* h0 = (const __half2*)&r0;
        const __half2* h1 = (const __half2*)&r1;
        #pragma unroll
        for (int q = 0; q < 4; q++) {
            float2 f0 = __half22float2(h0[q]);
            float2 f1 = __half22float2(h1[q]);
            acc[2 * q]     = fmaf(p0, f0.x, acc[2 * q]);
            acc[2 * q + 1] = fmaf(p0, f0.y, acc[2 * q + 1]);
            acc[8 + 2 * q]     = fmaf(p1, f1.x, acc[8 + 2 * q]);
            acc[8 + 2 * q + 1] = fmaf(p1, f1.y, acc[8 + 2 * q + 1]);
        }
        e = en; s = sn; asp = aspn; r0 = rn0; r1 = rn1;
    }
    // den reduce across the 16 lanes of the group
    #pragma unroll
    for (int m = 1; m < 16; m <<= 1) {
        den0 += __shfl_xor(den0, m, 64);
        den1 += __shfl_xor(den1, m, 64);
    }
    // 16x16 transpose-reduce via LDS (same-wave, no barrier needed)
    #pragma unroll
    for (int c = 0; c < 16; c++) sacc[t][c] = acc[c];
    float sum = 0.f;
    int rowb = g * 16;
    #pragma unroll
    for (int l = 0; l < 16; l++) sum += sacc[rowb + l][lane];

    float den = (lane < 8) ? den0 : den1;
    float o = sum / (den + 1e-16f) + b1[lane];
    o = (o > 0.f) ? o : 0.f;                     // ReLU
    float v = o * W2[lane];                      // fused (16 -> 1) @W2
    v += __shfl_xor(v, 1, 64);
    v += __shfl_xor(v, 2, 64);
    v += __shfl_xor(v, 4, 64);
    v += __shfl_xor(v, 8, 64);
    if (lane == 0) h2out[d] = v;
}

// ---------------- layer-2 edge pass (CSR walk) ----------------
__global__ __launch_bounds__(256) void k_edge2(
        const int* __restrict__ offs, const int* __restrict__ csr,
        const float* __restrict__ h2,
        const float* __restrict__ a_src2, const float* __restrict__ a_dst2,
        const float* __restrict__ b2, float* __restrict__ out) {
    int t = threadIdx.x;
    int g = t >> 4, lane = t & 15;
    int d = blockIdx.x * 16 + g;
    if (d >= N_NODES) return;

    float as2 = a_src2[0], ad2 = a_dst2[0];
    float adv = h2[d] * ad2;
    int beg = offs[d], end = offs[d + 1];

    float den = 0.f, acc = 0.f;
    for (int e = beg + lane; e < end; e += 16) {
        float hs = h2[csr[e]];
        float a = fmaf(hs, as2, adv);
        a = (a > 0.f) ? a : 0.2f * a;
        float p = __expf(a);
        den += p;
        acc = fmaf(p, hs, acc);
    }
    #pragma unroll
    for (int m = 1; m < 16; m <<= 1) {
        den += __shfl_xor(den, m, 64);
        acc += __shfl_xor(acc, m, 64);
    }
    if (lane == 0) out[d] = acc / (den + 1e-16f) + b2[0];
}

// ---------------- launch ----------------
extern "C" void kernel_launch(void* const* d_in, const int* in_sizes, int n_in,
                              void* d_out, int out_size, void* d_ws, size_t ws_size,
                              hipStream_t stream) {
    const float* x      = (const float*)d_in[0];
    const int*   edge   = (const int*)  d_in[1];
    const float* W1     = (const float*)d_in[2];
    const float* a_src1 = (const float*)d_in[3];
    const float* a_dst1 = (const float*)d_in[4];
    const float* b1     = (const float*)d_in[5];
    const float* W2     = (const float*)d_in[6];
    const float* a_src2 = (const float*)d_in[7];
    const float* a_dst2 = (const float*)d_in[8];
    const float* b2     = (const float*)d_in[9];

    constexpr size_t A = 256;
    auto al = [](size_t b) { return (b + A - 1) / A * A; };
    char* ws = (char*)d_ws;
    size_t off = 0;
    int*      flag   = (int*)(ws + off);      off += al(256);
    int*      ccnt   = (int*)(ws + off);      off += al((size_t)NCHUNK * NBUCK * 4); // 830 KB
    int*      bcnt   = (int*)(ws + off);      off += al(NBUCK * 4);
    int*      bbase  = (int*)(ws + off);      off += al((NBUCK + 1) * 4);
    unsigned* staged = (unsigned*)(ws + off); off += al((size_t)E_TOT * 4);          // 26 MB
    int*      csr    = (int*)(ws + off);      off += al((size_t)E_TOT * 4);          // 26 MB
    int*      offs   = (int*)(ws + off);      off += al((size_t)(N_NODES + 1) * 4);
    __half*   h16    = (__half*)(ws + off);   off += al((size_t)N_NODES * NHID * 2); // 3.2 MB
    float*    asrc   = (float*)(ws + off);    off += al((size_t)N_NODES * 2 * 4);    // 0.8 MB
    float*    adst   = (float*)(ws + off);    off += al((size_t)N_NODES * 2 * 4);    // 0.8 MB
    float*    h2     = (float*)(ws + off);    off += al((size_t)N_NODES * 4);
    (void)ws_size; (void)in_sizes; (void)n_in; (void)out_size;

    k_detect<<<1, 64, 0, stream>>>(edge, flag);
    k_gemm1 <<<(N_NODES + 15) / 16, 256, 0, stream>>>(x, W1, a_src1, a_dst1, h16, asrc, adst);
    k_ccount<<<NCHUNK, 256, 0, stream>>>(edge, flag, ccnt);
    k_cscan <<<NBUCK, 256, 0, stream>>>(ccnt, bcnt);
    k_bscan <<<1, 256, 0, stream>>>(bcnt, bbase);
    k_bin   <<<NCHUNK, 256, 0, stream>>>(edge, flag, ccnt, bbase, staged);
    k_sort  <<<NBUCK, 1024, 0, stream>>>(staged, bbase, csr, offs);
    k_edge1 <<<(N_NODES + 15) / 16, 256, 0, stream>>>(offs, csr, h16, asrc, adst, b1, W2, h2);
    k_edge2 <<<(N_NODES + 15) / 16, 256, 0, stream>>>(offs, csr, h2, a_src2, a_dst2, b2,
                                                      (float*)d_out);
}

// Round 8
// 238.592 us; speedup vs baseline: 5.1250x; 1.1049x over previous
//
#include <hip/hip_runtime.h>
#include <hip/hip_fp16.h>
#include <cstdint>
#include <cstddef>

#define N_NODES 100000
#define E_EDGES 6400000
#define E_TOT   (E_EDGES + N_NODES)
#define IN_CH   128
#define NHID    16              // HEADS*HID
#define BSHIFT  9               // 512 dsts per bucket
#define BSZ     512
#define NBUCK   196             // ceil(100000/512)
#define CHUNK   6144            // edges per k_bin block
#define BCAP    72              // LDS staging capacity per bucket (mean 31.5)
#define NCHUNK  ((E_TOT + CHUNK - 1) / CHUNK)   // 1058

// ---------------- detection: int64 vs int32 edge_index ----------------
__global__ void k_detect(const int* __restrict__ edge, int* __restrict__ flag) {
    if (blockIdx.x == 0 && threadIdx.x == 0) {
        int odd_or = 0;
        for (int i = 0; i < 64; i++) odd_or |= edge[2 * i + 1];
        flag[0] = (odd_or == 0) ? 1 : 0;   // 1 => data is int64 little-endian
    }
}

__device__ __forceinline__ int load_src(const int* e, size_t i, int m64) {
    return m64 ? e[2 * i] : e[i];
}
__device__ __forceinline__ int load_dst(const int* e, size_t i, int m64) {
    return m64 ? e[2 * ((size_t)E_EDGES + i)] : e[(size_t)E_EDGES + i];
}

// ------- layer-1 node features: h16 = fp16(x@W1), split alpha arrays --
__global__ __launch_bounds__(256) void k_gemm1(
        const float* __restrict__ x, const float* __restrict__ W1,
        const float* __restrict__ a_src1, const float* __restrict__ a_dst1,
        __half* __restrict__ h16, float* __restrict__ asrc,
        float* __restrict__ adst) {
    __shared__ __align__(16) float sW[IN_CH * NHID];   // 8 KB
    __shared__ __align__(16) float sx[16][132];        // padded stride
    __shared__ float sh[16][17];
    int t = threadIdx.x;
    int r = t >> 4, c = t & 15;
    int row = blockIdx.x * 16 + r;

    const float4* W4 = (const float4*)W1;
    ((float4*)sW)[t] = W4[t];
    ((float4*)sW)[t + 256] = W4[t + 256];

    if (row < N_NODES) {
        const float4* xr = (const float4*)(x + (size_t)row * IN_CH);
        float4 v0 = xr[c];
        float4 v1 = xr[c + 16];
        *(float4*)&sx[r][4 * c] = v0;
        *(float4*)&sx[r][64 + 4 * c] = v1;
    }
    __syncthreads();

    float acc = 0.f;
    if (row < N_NODES) {
        #pragma unroll 16
        for (int k = 0; k < IN_CH; k++) acc = fmaf(sx[r][k], sW[k * NHID + c], acc);
        h16[(size_t)row * NHID + c] = __float2half(acc);
    }
    sh[r][c] = acc;
    __syncthreads();

    if (row < N_NODES && c < 4) {
        int h = c & 1;
        const float* av = (c >= 2) ? a_dst1 : a_src1;
        float s = 0.f;
        #pragma unroll
        for (int q = 0; q < 8; q++) s = fmaf(sh[r][h * 8 + q], av[h * 8 + q], s);
        if (c < 2) asrc[2 * (size_t)row + c] = s;
        else       adst[2 * (size_t)row + (c - 2)] = s;
    }
}

// --- per-chunk 196-bucket histogram; int4-vectorized edge reads -------
__global__ __launch_bounds__(256) void k_ccount(const int* __restrict__ edge,
                                                const int* __restrict__ flag,
                                                int* __restrict__ ccnt) {
    __shared__ int sc[NBUCK];
    int m64 = flag[0];
    int t = threadIdx.x;
    for (int i = t; i < NBUCK; i += 256) sc[i] = 0;
    __syncthreads();
    size_t c0 = (size_t)blockIdx.x * CHUNK;
    size_t cend = c0 + CHUNK; if (cend > E_TOT) cend = E_TOT;
    size_t ee = (cend < (size_t)E_EDGES) ? cend : (size_t)E_EDGES;

    if (m64) {
        const int4* dp = (const int4*)(edge + 2 * (size_t)E_EDGES);
        for (size_t i = c0 + 2 * t; i < ee; i += 512) {
            int4 v = dp[i >> 1];                 // dsts of edges i, i+1
            atomicAdd(&sc[v.x >> BSHIFT], 1);
            if (i + 1 < ee) atomicAdd(&sc[v.z >> BSHIFT], 1);
        }
    } else {
        const int4* dp = (const int4*)(edge + (size_t)E_EDGES);
        for (size_t i = c0 + 4 * t; i < ee; i += 1024) {
            int4 v = dp[i >> 2];                 // dsts of edges i..i+3
            atomicAdd(&sc[v.x >> BSHIFT], 1);
            if (i + 1 < ee) atomicAdd(&sc[v.y >> BSHIFT], 1);
            if (i + 2 < ee) atomicAdd(&sc[v.z >> BSHIFT], 1);
            if (i + 3 < ee) atomicAdd(&sc[v.w >> BSHIFT], 1);
        }
    }
    size_t sl0 = (c0 > (size_t)E_EDGES) ? c0 : (size_t)E_EDGES;
    for (size_t i = sl0 + t; i < cend; i += 256) {
        int d = (int)(i - E_EDGES);              // self-loop: no memory read
        atomicAdd(&sc[d >> BSHIFT], 1);
    }
    __syncthreads();
    for (int i = t; i < NBUCK; i += 256)
        ccnt[(size_t)blockIdx.x * NBUCK + i] = sc[i];
}

// --- per-bucket exclusive scan over chunks: exact per-chunk bases -----
__global__ __launch_bounds__(256) void k_cscan(int* __restrict__ ccnt,
                                               int* __restrict__ bcnt) {
    __shared__ int sd[256];
    __shared__ int carry;
    int b = blockIdx.x, t = threadIdx.x;
    if (t == 0) carry = 0;
    __syncthreads();
    for (int base = 0; base < NCHUNK; base += 256) {
        int c = base + t;
        int v = (c < NCHUNK) ? ccnt[(size_t)c * NBUCK + b] : 0;
        sd[t] = v;
        __syncthreads();
        for (int ofs = 1; ofs < 256; ofs <<= 1) {
            int a = sd[t];
            int bb = (t >= ofs) ? sd[t - ofs] : 0;
            __syncthreads();
            sd[t] = a + bb;
            __syncthreads();
        }
        if (c < NCHUNK) ccnt[(size_t)c * NBUCK + b] = sd[t] - v + carry;
        __syncthreads();
        if (t == 255) carry += sd[255];
        __syncthreads();
    }
    if (t == 0) bcnt[b] = carry;
}

// ---------------- tiny scan over 196 bucket totals ----------------
__global__ void k_bscan(const int* __restrict__ bcnt, int* __restrict__ bbase) {
    __shared__ int sd[256];
    int t = threadIdx.x;
    int v = (t < NBUCK) ? bcnt[t] : 0;
    sd[t] = v;
    __syncthreads();
    for (int ofs = 1; ofs < 256; ofs <<= 1) {
        int a = sd[t];
        int b = (t >= ofs) ? sd[t - ofs] : 0;
        __syncthreads();
        sd[t] = a + b;
        __syncthreads();
    }
    if (t < NBUCK) bbase[t] = sd[t] - v;        // exclusive
    if (t == NBUCK) bbase[NBUCK] = sd[NBUCK - 1];
}

// ------ binning with precomputed exact slots: ZERO global atomics -----
__global__ __launch_bounds__(256) void k_bin(const int* __restrict__ edge,
                                             const int* __restrict__ flag,
                                             const int* __restrict__ ccnt,
                                             const int* __restrict__ bbase,
                                             unsigned* __restrict__ staged) {
    __shared__ unsigned lbin[NBUCK][BCAP];   // 55 KB
    __shared__ int lcnt[NBUCK];
    __shared__ int lbase[NBUCK];
    int m64 = flag[0];
    int t = threadIdx.x;
    int g = t >> 4, lane = t & 15;

    size_t c0 = (size_t)blockIdx.x * CHUNK;
    if (c0 >= E_TOT) return;
    size_t cend = c0 + CHUNK; if (cend > E_TOT) cend = E_TOT;
    size_t ee = (cend < (size_t)E_EDGES) ? cend : (size_t)E_EDGES;

    for (int i = t; i < NBUCK; i += 256) {
        lcnt[i] = 0;
        lbase[i] = bbase[i] + ccnt[(size_t)blockIdx.x * NBUCK + i];
    }
    __syncthreads();

    auto put = [&](int s, int d) {
        int b = d >> BSHIFT;
        unsigned v = (unsigned)s | ((unsigned)(d & (BSZ - 1)) << 17);
        int idx = atomicAdd(&lcnt[b], 1);
        if (idx < BCAP) lbin[b][idx] = v;
        else            staged[lbase[b] + idx] = v;   // exact slot, no atomic
    };

    if (m64) {
        const int4* sp = (const int4*)edge;
        const int4* dp = (const int4*)(edge + 2 * (size_t)E_EDGES);
        for (size_t i = c0 + 2 * t; i < ee; i += 512) {
            int4 sv = sp[i >> 1];
            int4 dv = dp[i >> 1];
            put(sv.x, dv.x);
            if (i + 1 < ee) put(sv.z, dv.z);
        }
    } else {
        const int4* sp = (const int4*)edge;
        const int4* dp = (const int4*)(edge + (size_t)E_EDGES);
        for (size_t i = c0 + 4 * t; i < ee; i += 1024) {
            int4 sv = sp[i >> 2];
            int4 dv = dp[i >> 2];
            put(sv.x, dv.x);
            if (i + 1 < ee) put(sv.y, dv.y);
            if (i + 2 < ee) put(sv.z, dv.z);
            if (i + 3 < ee) put(sv.w, dv.w);
        }
    }
    size_t sl0 = (c0 > (size_t)E_EDGES) ? c0 : (size_t)E_EDGES;
    for (size_t i = sl0 + t; i < cend; i += 256) {
        int d = (int)(i - E_EDGES);
        put(d, d);
    }
    __syncthreads();
    // cooperative coalesced flush of the LDS-staged majority
    for (int b = g; b < NBUCK; b += 16) {
        int n = min(lcnt[b], BCAP);
        if (!n) continue;
        int pos = lbase[b];
        for (int i = lane; i < n; i += 16) staged[pos + i] = lbin[b][i];
    }
}

// -- per-bucket counting sort -> CSR; 2 blocks/bucket (edge-range split)
__global__ __launch_bounds__(1024) void k_sort(const unsigned* __restrict__ staged,
                                               const int* __restrict__ bbase,
                                               int* __restrict__ csr,
                                               int* __restrict__ offs) {
    __shared__ int hist[BSZ];
    __shared__ int histlo[BSZ];
    __shared__ int lcur[BSZ];
    int bkt = blockIdx.x >> 1, p = blockIdx.x & 1;
    int t = threadIdx.x;
    int beg = bbase[bkt], end = bbase[bkt + 1];
    int mid = beg + ((end - beg + 1) >> 1);
    int dbase = bkt << BSHIFT;

    if (t < BSZ) { hist[t] = 0; histlo[t] = 0; }
    __syncthreads();
    for (int e = beg + t; e < end; e += 1024) {
        int dl = staged[e] >> 17;
        atomicAdd(&hist[dl], 1);
        if (e < mid) atomicAdd(&histlo[dl], 1);
    }
    __syncthreads();

    int myv = (t < BSZ) ? hist[t] : 0;
    __syncthreads();
    for (int ofs = 1; ofs < BSZ; ofs <<= 1) {
        int a = 0, b = 0;
        if (t < BSZ) { a = hist[t]; b = (t >= ofs) ? hist[t - ofs] : 0; }
        __syncthreads();
        if (t < BSZ) hist[t] = a + b;
        __syncthreads();
    }
    if (t < BSZ) {
        int excl = hist[t] - myv;
        lcur[t] = excl + (p ? histlo[t] : 0);
        if (p == 0) {
            int dd = dbase + t;
            if (dd < N_NODES) offs[dd] = beg + excl;
        }
    }
    if (bkt == NBUCK - 1 && p == 0 && t == 0) offs[N_NODES] = E_TOT;
    __syncthreads();

    int lo = p ? mid : beg;
    int hi = p ? end : mid;
    for (int e = lo + t; e < hi; e += 1024) {
        unsigned v = staged[e];
        int pos = atomicAdd(&lcur[v >> 17], 1);
        csr[beg + pos] = (int)(v & 0x1FFFFu);   // 133 KB window: L2-resident
    }
}

// --- layer-1 edge pass: lane=edge, 4-deep slot pipeline ---------------
// Each lane owns one edge per slot; 4 slots keep ~12-16 loads in flight
// (csr + asrc + 2x float4 row each). Final 16x16 transpose-reduce via
// padded LDS (2-way bank aliasing = free).
__global__ __launch_bounds__(256) void k_edge1(
        const int* __restrict__ offs, const int* __restrict__ csr,
        const __half* __restrict__ h16, const float* __restrict__ asrc,
        const float* __restrict__ adst,
        const float* __restrict__ b1, const float* __restrict__ W2,
        float* __restrict__ h2out) {
    __shared__ float sacc[256][17];   // 17.4 KB, padded
    int t = threadIdx.x;
    int lane = t & 15;
    int g = t >> 4;
    int d = blockIdx.x * 16 + g;
    if (d >= N_NODES) return;

    float2 adp = ((const float2*)adst)[d];
    int beg = offs[d], end = offs[d + 1];

    float acc[16];
    #pragma unroll
    for (int c = 0; c < 16; c++) acc[c] = 0.f;
    float den0 = 0.f, den1 = 0.f;

    auto loadslot = [&](int ee, float2& asp, float4& r0, float4& r1) {
        if (ee < end) {
            int s = csr[ee];
            asp = ((const float2*)asrc)[s];
            const float4* hp = (const float4*)(h16 + (size_t)s * NHID);
            r0 = hp[0]; r1 = hp[1];
        }
    };
    auto consume = [&](const float2& asp, const float4& r0, const float4& r1) {
        float a0 = asp.x + adp.x; a0 = (a0 > 0.f) ? a0 : 0.2f * a0;
        float a1 = asp.y + adp.y; a1 = (a1 > 0.f) ? a1 : 0.2f * a1;
        float p0 = __expf(a0), p1 = __expf(a1);
        den0 += p0; den1 += p1;
        const __half2* h0 = (const __half2*)&r0;
        const __half2* h1 = (const __half2*)&r1;
        #pragma unroll
        for (int q = 0; q < 4; q++) {
            float2 f0 = __half22float2(h0[q]);
            float2 f1 = __half22float2(h1[q]);
            acc[2 * q]         = fmaf(p0, f0.x, acc[2 * q]);
            acc[2 * q + 1]     = fmaf(p0, f0.y, acc[2 * q + 1]);
            acc[8 + 2 * q]     = fmaf(p1, f1.x, acc[8 + 2 * q]);
            acc[8 + 2 * q + 1] = fmaf(p1, f1.y, acc[8 + 2 * q + 1]);
        }
    };

    float2 aspA{}, aspB{}, aspC{}, aspD{};
    float4 z4 = make_float4(0.f, 0.f, 0.f, 0.f);
    float4 r0A = z4, r1A = z4, r0B = z4, r1B = z4;
    float4 r0C = z4, r1C = z4, r0D = z4, r1D = z4;

    int e = beg + lane;
    loadslot(e,      aspA, r0A, r1A);
    loadslot(e + 16, aspB, r0B, r1B);
    loadslot(e + 32, aspC, r0C, r1C);
    loadslot(e + 48, aspD, r0D, r1D);
    while (true) {
        if (e >= end) break;
        consume(aspA, r0A, r1A); loadslot(e + 64, aspA, r0A, r1A); e += 16;
        if (e >= end) break;
        consume(aspB, r0B, r1B); loadslot(e + 64, aspB, r0B, r1B); e += 16;
        if (e >= end) break;
        consume(aspC, r0C, r1C); loadslot(e + 64, aspC, r0C, r1C); e += 16;
        if (e >= end) break;
        consume(aspD, r0D, r1D); loadslot(e + 64, aspD, r0D, r1D); e += 16;
    }
    // den reduce across the 16 lanes of the group
    #pragma unroll
    for (int m = 1; m < 16; m <<= 1) {
        den0 += __shfl_xor(den0, m, 64);
        den1 += __shfl_xor(den1, m, 64);
    }
    // 16x16 transpose-reduce via LDS (same-wave, no barrier needed)
    #pragma unroll
    for (int c = 0; c < 16; c++) sacc[t][c] = acc[c];
    float sum = 0.f;
    int rowb = g * 16;
    #pragma unroll
    for (int l = 0; l < 16; l++) sum += sacc[rowb + l][lane];

    float den = (lane < 8) ? den0 : den1;
    float o = sum / (den + 1e-16f) + b1[lane];
    o = (o > 0.f) ? o : 0.f;                     // ReLU
    float v = o * W2[lane];                      // fused (16 -> 1) @W2
    v += __shfl_xor(v, 1, 64);
    v += __shfl_xor(v, 2, 64);
    v += __shfl_xor(v, 4, 64);
    v += __shfl_xor(v, 8, 64);
    if (lane == 0) h2out[d] = v;
}

// ------------- layer-2 edge pass (CSR walk, 4-deep pipeline) ----------
__global__ __launch_bounds__(256) void k_edge2(
        const int* __restrict__ offs, const int* __restrict__ csr,
        const float* __restrict__ h2,
        const float* __restrict__ a_src2, const float* __restrict__ a_dst2,
        const float* __restrict__ b2, float* __restrict__ out) {
    int t = threadIdx.x;
    int g = t >> 4, lane = t & 15;
    int d = blockIdx.x * 16 + g;
    if (d >= N_NODES) return;

    float as2 = a_src2[0], ad2 = a_dst2[0];
    float adv = h2[d] * ad2;
    int beg = offs[d], end = offs[d + 1];

    float den = 0.f, acc = 0.f;
    auto ls = [&](int ee, float& hs) { if (ee < end) hs = h2[csr[ee]]; };
    auto cs = [&](float hs) {
        float a = fmaf(hs, as2, adv);
        a = (a > 0.f) ? a : 0.2f * a;
        float p = __expf(a);
        den += p;
        acc = fmaf(p, hs, acc);
    };
    float hA = 0.f, hB = 0.f, hC = 0.f, hD = 0.f;
    int e = beg + lane;
    ls(e, hA); ls(e + 16, hB); ls(e + 32, hC); ls(e + 48, hD);
    while (true) {
        if (e >= end) break;
        cs(hA); ls(e + 64, hA); e += 16;
        if (e >= end) break;
        cs(hB); ls(e + 64, hB); e += 16;
        if (e >= end) break;
        cs(hC); ls(e + 64, hC); e += 16;
        if (e >= end) break;
        cs(hD); ls(e + 64, hD); e += 16;
    }
    #pragma unroll
    for (int m = 1; m < 16; m <<= 1) {
        den += __shfl_xor(den, m, 64);
        acc += __shfl_xor(acc, m, 64);
    }
    if (lane == 0) out[d] = acc / (den + 1e-16f) + b2[0];
}

// ---------------- launch ----------------
extern "C" void kernel_launch(void* const* d_in, const int* in_sizes, int n_in,
                              void* d_out, int out_size, void* d_ws, size_t ws_size,
                              hipStream_t stream) {
    const float* x      = (const float*)d_in[0];
    const int*   edge   = (const int*)  d_in[1];
    const float* W1     = (const float*)d_in[2];
    const float* a_src1 = (const float*)d_in[3];
    const float* a_dst1 = (const float*)d_in[4];
    const float* b1     = (const float*)d_in[5];
    const float* W2     = (const float*)d_in[6];
    const float* a_src2 = (const float*)d_in[7];
    const float* a_dst2 = (const float*)d_in[8];
    const float* b2     = (const float*)d_in[9];

    constexpr size_t A = 256;
    auto al = [](size_t b) { return (b + A - 1) / A * A; };
    char* ws = (char*)d_ws;
    size_t off = 0;
    int*      flag   = (int*)(ws + off);      off += al(256);
    int*      ccnt   = (int*)(ws + off);      off += al((size_t)NCHUNK * NBUCK * 4); // 830 KB
    int*      bcnt   = (int*)(ws + off);      off += al(NBUCK * 4);
    int*      bbase  = (int*)(ws + off);      off += al((NBUCK + 1) * 4);
    unsigned* staged = (unsigned*)(ws + off); off += al((size_t)E_TOT * 4);          // 26 MB
    int*      csr    = (int*)(ws + off);      off += al((size_t)E_TOT * 4);          // 26 MB
    int*      offs   = (int*)(ws + off);      off += al((size_t)(N_NODES + 1) * 4);
    __half*   h16    = (__half*)(ws + off);   off += al((size_t)N_NODES * NHID * 2); // 3.2 MB
    float*    asrc   = (float*)(ws + off);    off += al((size_t)N_NODES * 2 * 4);    // 0.8 MB
    float*    adst   = (float*)(ws + off);    off += al((size_t)N_NODES * 2 * 4);    // 0.8 MB
    float*    h2     = (float*)(ws + off);    off += al((size_t)N_NODES * 4);
    (void)ws_size; (void)in_sizes; (void)n_in; (void)out_size;

    k_detect<<<1, 64, 0, stream>>>(edge, flag);
    k_gemm1 <<<(N_NODES + 15) / 16, 256, 0, stream>>>(x, W1, a_src1, a_dst1, h16, asrc, adst);
    k_ccount<<<NCHUNK, 256, 0, stream>>>(edge, flag, ccnt);
    k_cscan <<<NBUCK, 256, 0, stream>>>(ccnt, bcnt);
    k_bscan <<<1, 256, 0, stream>>>(bcnt, bbase);
    k_bin   <<<NCHUNK, 256, 0, stream>>>(edge, flag, ccnt, bbase, staged);
    k_sort  <<<NBUCK * 2, 1024, 0, stream>>>(staged, bbase, csr, offs);
    k_edge1 <<<(N_NODES + 15) / 16, 256, 0, stream>>>(offs, csr, h16, asrc, adst, b1, W2, h2);
    k_edge2 <<<(N_NODES + 15) / 16, 256, 0, stream>>>(offs, csr, h2, a_src2, a_dst2, b2,
                                                      (float*)d_out);
}

// Round 9
// 219.329 us; speedup vs baseline: 5.5751x; 1.0878x over previous
//
#include <hip/hip_runtime.h>
#include <hip/hip_fp16.h>
#include <cstdint>
#include <cstddef>

#define N_NODES 100000
#define E_EDGES 6400000
#define E_TOT   (E_EDGES + N_NODES)
#define IN_CH   128
#define NHID    16              // HEADS*HID
#define RECB    64              // bytes per node record: h16[16] + asrc0/1 + pad
#define BSHIFT  9               // 512 dsts per bucket
#define BSZ     512
#define NBUCK   196             // ceil(100000/512)
#define CHUNK   6144            // edges per k_bin block
#define BCAP    48              // LDS staging capacity per bucket (mean 31.3)
#define NCHUNK  ((E_TOT + CHUNK - 1) / CHUNK)   // 1058

// ---------------- detection: int64 vs int32 edge_index ----------------
__global__ void k_detect(const int* __restrict__ edge, int* __restrict__ flag) {
    if (blockIdx.x == 0 && threadIdx.x == 0) {
        int odd_or = 0;
        for (int i = 0; i < 64; i++) odd_or |= edge[2 * i + 1];
        flag[0] = (odd_or == 0) ? 1 : 0;   // 1 => data is int64 little-endian
    }
}

// ------- layer-1 node features: 64B record {h16 row, asrc pair} -------
__global__ __launch_bounds__(256) void k_gemm1(
        const float* __restrict__ x, const float* __restrict__ W1,
        const float* __restrict__ a_src1, const float* __restrict__ a_dst1,
        char* __restrict__ rec, float* __restrict__ adst) {
    __shared__ __align__(16) float sW[IN_CH * NHID];   // 8 KB
    __shared__ __align__(16) float sx[16][132];        // padded stride
    __shared__ float sh[16][17];
    int t = threadIdx.x;
    int r = t >> 4, c = t & 15;
    int row = blockIdx.x * 16 + r;

    const float4* W4 = (const float4*)W1;
    ((float4*)sW)[t] = W4[t];
    ((float4*)sW)[t + 256] = W4[t + 256];

    if (row < N_NODES) {
        const float4* xr = (const float4*)(x + (size_t)row * IN_CH);
        float4 v0 = xr[c];
        float4 v1 = xr[c + 16];
        *(float4*)&sx[r][4 * c] = v0;
        *(float4*)&sx[r][64 + 4 * c] = v1;
    }
    __syncthreads();

    float acc = 0.f;
    if (row < N_NODES) {
        #pragma unroll 16
        for (int k = 0; k < IN_CH; k++) acc = fmaf(sx[r][k], sW[k * NHID + c], acc);
        ((__half*)(rec + (size_t)row * RECB))[c] = __float2half(acc);
    }
    sh[r][c] = acc;
    __syncthreads();

    if (row < N_NODES && c < 4) {
        int h = c & 1;
        const float* av = (c >= 2) ? a_dst1 : a_src1;
        float s = 0.f;
        #pragma unroll
        for (int q = 0; q < 8; q++) s = fmaf(sh[r][h * 8 + q], av[h * 8 + q], s);
        if (c < 2) ((float*)(rec + (size_t)row * RECB + 32))[c] = s;
        else       adst[2 * (size_t)row + (c - 2)] = s;
    }
}

// --- per-chunk 196-bucket histogram; int4-vectorized edge reads -------
__global__ __launch_bounds__(256) void k_ccount(const int* __restrict__ edge,
                                                const int* __restrict__ flag,
                                                int* __restrict__ ccnt) {
    __shared__ int sc[NBUCK];
    int m64 = flag[0];
    int t = threadIdx.x;
    for (int i = t; i < NBUCK; i += 256) sc[i] = 0;
    __syncthreads();
    size_t c0 = (size_t)blockIdx.x * CHUNK;
    size_t cend = c0 + CHUNK; if (cend > E_TOT) cend = E_TOT;
    size_t ee = (cend < (size_t)E_EDGES) ? cend : (size_t)E_EDGES;

    if (m64) {
        const int4* dp = (const int4*)(edge + 2 * (size_t)E_EDGES);
        for (size_t i = c0 + 2 * t; i < ee; i += 512) {
            int4 v = dp[i >> 1];                 // dsts of edges i, i+1
            atomicAdd(&sc[v.x >> BSHIFT], 1);
            if (i + 1 < ee) atomicAdd(&sc[v.z >> BSHIFT], 1);
        }
    } else {
        const int4* dp = (const int4*)(edge + (size_t)E_EDGES);
        for (size_t i = c0 + 4 * t; i < ee; i += 1024) {
            int4 v = dp[i >> 2];                 // dsts of edges i..i+3
            atomicAdd(&sc[v.x >> BSHIFT], 1);
            if (i + 1 < ee) atomicAdd(&sc[v.y >> BSHIFT], 1);
            if (i + 2 < ee) atomicAdd(&sc[v.z >> BSHIFT], 1);
            if (i + 3 < ee) atomicAdd(&sc[v.w >> BSHIFT], 1);
        }
    }
    size_t sl0 = (c0 > (size_t)E_EDGES) ? c0 : (size_t)E_EDGES;
    for (size_t i = sl0 + t; i < cend; i += 256) {
        int d = (int)(i - E_EDGES);              // self-loop: no memory read
        atomicAdd(&sc[d >> BSHIFT], 1);
    }
    __syncthreads();
    for (int i = t; i < NBUCK; i += 256)
        ccnt[(size_t)blockIdx.x * NBUCK + i] = sc[i];
}

// --- per-bucket exclusive scan over chunks: exact per-chunk bases -----
__global__ __launch_bounds__(256) void k_cscan(int* __restrict__ ccnt,
                                               int* __restrict__ bcnt) {
    __shared__ int sd[256];
    __shared__ int carry;
    int b = blockIdx.x, t = threadIdx.x;
    if (t == 0) carry = 0;
    __syncthreads();
    for (int base = 0; base < NCHUNK; base += 256) {
        int c = base + t;
        int v = (c < NCHUNK) ? ccnt[(size_t)c * NBUCK + b] : 0;
        sd[t] = v;
        __syncthreads();
        for (int ofs = 1; ofs < 256; ofs <<= 1) {
            int a = sd[t];
            int bb = (t >= ofs) ? sd[t - ofs] : 0;
            __syncthreads();
            sd[t] = a + bb;
            __syncthreads();
        }
        if (c < NCHUNK) ccnt[(size_t)c * NBUCK + b] = sd[t] - v + carry;
        __syncthreads();
        if (t == 255) carry += sd[255];
        __syncthreads();
    }
    if (t == 0) bcnt[b] = carry;
}

// ---------------- tiny scan over 196 bucket totals ----------------
__global__ void k_bscan(const int* __restrict__ bcnt, int* __restrict__ bbase) {
    __shared__ int sd[256];
    int t = threadIdx.x;
    int v = (t < NBUCK) ? bcnt[t] : 0;
    sd[t] = v;
    __syncthreads();
    for (int ofs = 1; ofs < 256; ofs <<= 1) {
        int a = sd[t];
        int b = (t >= ofs) ? sd[t - ofs] : 0;
        __syncthreads();
        sd[t] = a + b;
        __syncthreads();
    }
    if (t < NBUCK) bbase[t] = sd[t] - v;        // exclusive
    if (t == NBUCK) bbase[NBUCK] = sd[NBUCK - 1];
}

// ------ binning with precomputed exact slots: ZERO global atomics -----
__global__ __launch_bounds__(256) void k_bin(const int* __restrict__ edge,
                                             const int* __restrict__ flag,
                                             const int* __restrict__ ccnt,
                                             const int* __restrict__ bbase,
                                             unsigned* __restrict__ staged) {
    __shared__ unsigned lbin[NBUCK][BCAP];   // 37.6 KB -> 4 blocks/CU
    __shared__ int lcnt[NBUCK];
    __shared__ int lbase[NBUCK];
    int m64 = flag[0];
    int t = threadIdx.x;
    int g = t >> 4, lane = t & 15;

    size_t c0 = (size_t)blockIdx.x * CHUNK;
    if (c0 >= E_TOT) return;
    size_t cend = c0 + CHUNK; if (cend > E_TOT) cend = E_TOT;
    size_t ee = (cend < (size_t)E_EDGES) ? cend : (size_t)E_EDGES;

    for (int i = t; i < NBUCK; i += 256) {
        lcnt[i] = 0;
        lbase[i] = bbase[i] + ccnt[(size_t)blockIdx.x * NBUCK + i];
    }
    __syncthreads();

    auto put = [&](int s, int d) {
        int b = d >> BSHIFT;
        unsigned v = (unsigned)s | ((unsigned)(d & (BSZ - 1)) << 17);
        int idx = atomicAdd(&lcnt[b], 1);
        if (idx < BCAP) lbin[b][idx] = v;
        else            staged[lbase[b] + idx] = v;   // exact slot, no atomic
    };

    if (m64) {
        const int4* sp = (const int4*)edge;
        const int4* dp = (const int4*)(edge + 2 * (size_t)E_EDGES);
        for (size_t i = c0 + 2 * t; i < ee; i += 512) {
            int4 sv = sp[i >> 1];
            int4 dv = dp[i >> 1];
            put(sv.x, dv.x);
            if (i + 1 < ee) put(sv.z, dv.z);
        }
    } else {
        const int4* sp = (const int4*)edge;
        const int4* dp = (const int4*)(edge + (size_t)E_EDGES);
        for (size_t i = c0 + 4 * t; i < ee; i += 1024) {
            int4 sv = sp[i >> 2];
            int4 dv = dp[i >> 2];
            put(sv.x, dv.x);
            if (i + 1 < ee) put(sv.y, dv.y);
            if (i + 2 < ee) put(sv.z, dv.z);
            if (i + 3 < ee) put(sv.w, dv.w);
        }
    }
    size_t sl0 = (c0 > (size_t)E_EDGES) ? c0 : (size_t)E_EDGES;
    for (size_t i = sl0 + t; i < cend; i += 256) {
        int d = (int)(i - E_EDGES);
        put(d, d);
    }
    __syncthreads();
    // cooperative coalesced flush of the LDS-staged majority
    for (int b = g; b < NBUCK; b += 16) {
        int n = min(lcnt[b], BCAP);
        if (!n) continue;
        int pos = lbase[b];
        for (int i = lane; i < n; i += 16) staged[pos + i] = lbin[b][i];
    }
}

// -- per-bucket counting sort -> CSR; 2 blocks/bucket (edge-range split)
__global__ __launch_bounds__(1024) void k_sort(const unsigned* __restrict__ staged,
                                               const int* __restrict__ bbase,
                                               int* __restrict__ csr,
                                               int* __restrict__ offs) {
    __shared__ int hist[BSZ];
    __shared__ int histlo[BSZ];
    __shared__ int lcur[BSZ];
    int bkt = blockIdx.x >> 1, p = blockIdx.x & 1;
    int t = threadIdx.x;
    int beg = bbase[bkt], end = bbase[bkt + 1];
    int mid = beg + ((end - beg + 1) >> 1);
    int dbase = bkt << BSHIFT;

    if (t < BSZ) { hist[t] = 0; histlo[t] = 0; }
    __syncthreads();
    for (int e = beg + t; e < end; e += 1024) {
        int dl = staged[e] >> 17;
        atomicAdd(&hist[dl], 1);
        if (e < mid) atomicAdd(&histlo[dl], 1);
    }
    __syncthreads();

    int myv = (t < BSZ) ? hist[t] : 0;
    __syncthreads();
    for (int ofs = 1; ofs < BSZ; ofs <<= 1) {
        int a = 0, b = 0;
        if (t < BSZ) { a = hist[t]; b = (t >= ofs) ? hist[t - ofs] : 0; }
        __syncthreads();
        if (t < BSZ) hist[t] = a + b;
        __syncthreads();
    }
    if (t < BSZ) {
        int excl = hist[t] - myv;
        lcur[t] = excl + (p ? histlo[t] : 0);
        if (p == 0) {
            int dd = dbase + t;
            if (dd < N_NODES) offs[dd] = beg + excl;
        }
    }
    if (bkt == NBUCK - 1 && p == 0 && t == 0) offs[N_NODES] = E_TOT;
    __syncthreads();

    int lo = p ? mid : beg;
    int hi = p ? end : mid;
    for (int e = lo + t; e < hi; e += 1024) {
        unsigned v = staged[e];
        int pos = atomicAdd(&lcur[v >> 17], 1);
        csr[beg + pos] = (int)(v & 0x1FFFFu);   // 133 KB window: L2-resident
    }
}

// --- layer-1 edge pass: lane=edge, 6-deep pipeline, 1 line per edge ---
__global__ __launch_bounds__(256) void k_edge1(
        const int* __restrict__ offs, const int* __restrict__ csr,
        const char* __restrict__ rec, const float* __restrict__ adst,
        const float* __restrict__ b1, const float* __restrict__ W2,
        float* __restrict__ h2out) {
    __shared__ float sacc[256][17];   // 17.4 KB, padded
    int t = threadIdx.x;
    int lane = t & 15;
    int g = t >> 4;
    int d = blockIdx.x * 16 + g;
    if (d >= N_NODES) return;

    float2 adp = ((const float2*)adst)[d];
    int beg = offs[d], end = offs[d + 1];

    float acc[16];
    #pragma unroll
    for (int c = 0; c < 16; c++) acc[c] = 0.f;
    float den0 = 0.f, den1 = 0.f;

    auto loadslot = [&](int ee, float2& asp, float4& r0, float4& r1) {
        if (ee < end) {
            int s = csr[ee];
            const char* rp = rec + (size_t)s * RECB;
            r0 = ((const float4*)rp)[0];
            r1 = ((const float4*)rp)[1];
            asp = *(const float2*)(rp + 32);     // same 64B line
        }
    };
    auto consume = [&](const float2& asp, const float4& r0, const float4& r1) {
        float a0 = asp.x + adp.x; a0 = (a0 > 0.f) ? a0 : 0.2f * a0;
        float a1 = asp.y + adp.y; a1 = (a1 > 0.f) ? a1 : 0.2f * a1;
        float p0 = __expf(a0), p1 = __expf(a1);
        den0 += p0; den1 += p1;
        const __half2* h0 = (const __half2*)&r0;
        const __half2* h1 = (const __half2*)&r1;
        #pragma unroll
        for (int q = 0; q < 4; q++) {
            float2 f0 = __half22float2(h0[q]);
            float2 f1 = __half22float2(h1[q]);
            acc[2 * q]         = fmaf(p0, f0.x, acc[2 * q]);
            acc[2 * q + 1]     = fmaf(p0, f0.y, acc[2 * q + 1]);
            acc[8 + 2 * q]     = fmaf(p1, f1.x, acc[8 + 2 * q]);
            acc[8 + 2 * q + 1] = fmaf(p1, f1.y, acc[8 + 2 * q + 1]);
        }
    };

    float2 aspA{}, aspB{}, aspC{}, aspD{}, aspE{}, aspF{};
    float4 z4 = make_float4(0.f, 0.f, 0.f, 0.f);
    float4 r0A = z4, r1A = z4, r0B = z4, r1B = z4, r0C = z4, r1C = z4;
    float4 r0D = z4, r1D = z4, r0E = z4, r1E = z4, r0F = z4, r1F = z4;

    int e = beg + lane;
    loadslot(e,      aspA, r0A, r1A);
    loadslot(e + 16, aspB, r0B, r1B);
    loadslot(e + 32, aspC, r0C, r1C);
    loadslot(e + 48, aspD, r0D, r1D);
    loadslot(e + 64, aspE, r0E, r1E);
    loadslot(e + 80, aspF, r0F, r1F);
    while (true) {
        if (e >= end) break;
        consume(aspA, r0A, r1A); loadslot(e + 96, aspA, r0A, r1A); e += 16;
        if (e >= end) break;
        consume(aspB, r0B, r1B); loadslot(e + 96, aspB, r0B, r1B); e += 16;
        if (e >= end) break;
        consume(aspC, r0C, r1C); loadslot(e + 96, aspC, r0C, r1C); e += 16;
        if (e >= end) break;
        consume(aspD, r0D, r1D); loadslot(e + 96, aspD, r0D, r1D); e += 16;
        if (e >= end) break;
        consume(aspE, r0E, r1E); loadslot(e + 96, aspE, r0E, r1E); e += 16;
        if (e >= end) break;
        consume(aspF, r0F, r1F); loadslot(e + 96, aspF, r0F, r1F); e += 16;
    }
    // den reduce across the 16 lanes of the group
    #pragma unroll
    for (int m = 1; m < 16; m <<= 1) {
        den0 += __shfl_xor(den0, m, 64);
        den1 += __shfl_xor(den1, m, 64);
    }
    // 16x16 transpose-reduce via LDS (same-wave, no barrier needed)
    #pragma unroll
    for (int c = 0; c < 16; c++) sacc[t][c] = acc[c];
    float sum = 0.f;
    int rowb = g * 16;
    #pragma unroll
    for (int l = 0; l < 16; l++) sum += sacc[rowb + l][lane];

    float den = (lane < 8) ? den0 : den1;
    float o = sum / (den + 1e-16f) + b1[lane];
    o = (o > 0.f) ? o : 0.f;                     // ReLU
    float v = o * W2[lane];                      // fused (16 -> 1) @W2
    v += __shfl_xor(v, 1, 64);
    v += __shfl_xor(v, 2, 64);
    v += __shfl_xor(v, 4, 64);
    v += __shfl_xor(v, 8, 64);
    if (lane == 0) h2out[d] = v;
}

// ------------- layer-2 edge pass (CSR walk, 6-deep pipeline) ----------
__global__ __launch_bounds__(256) void k_edge2(
        const int* __restrict__ offs, const int* __restrict__ csr,
        const float* __restrict__ h2,
        const float* __restrict__ a_src2, const float* __restrict__ a_dst2,
        const float* __restrict__ b2, float* __restrict__ out) {
    int t = threadIdx.x;
    int g = t >> 4, lane = t & 15;
    int d = blockIdx.x * 16 + g;
    if (d >= N_NODES) return;

    float as2 = a_src2[0], ad2 = a_dst2[0];
    float adv = h2[d] * ad2;
    int beg = offs[d], end = offs[d + 1];

    float den = 0.f, acc = 0.f;
    auto ls = [&](int ee, float& hs) { if (ee < end) hs = h2[csr[ee]]; };
    auto cs = [&](float hs) {
        float a = fmaf(hs, as2, adv);
        a = (a > 0.f) ? a : 0.2f * a;
        float p = __expf(a);
        den += p;
        acc = fmaf(p, hs, acc);
    };
    float hA = 0.f, hB = 0.f, hC = 0.f, hD = 0.f, hE = 0.f, hF = 0.f;
    int e = beg + lane;
    ls(e, hA); ls(e + 16, hB); ls(e + 32, hC);
    ls(e + 48, hD); ls(e + 64, hE); ls(e + 80, hF);
    while (true) {
        if (e >= end) break;
        cs(hA); ls(e + 96, hA); e += 16;
        if (e >= end) break;
        cs(hB); ls(e + 96, hB); e += 16;
        if (e >= end) break;
        cs(hC); ls(e + 96, hC); e += 16;
        if (e >= end) break;
        cs(hD); ls(e + 96, hD); e += 16;
        if (e >= end) break;
        cs(hE); ls(e + 96, hE); e += 16;
        if (e >= end) break;
        cs(hF); ls(e + 96, hF); e += 16;
    }
    #pragma unroll
    for (int m = 1; m < 16; m <<= 1) {
        den += __shfl_xor(den, m, 64);
        acc += __shfl_xor(acc, m, 64);
    }
    if (lane == 0) out[d] = acc / (den + 1e-16f) + b2[0];
}

// ---------------- launch ----------------
extern "C" void kernel_launch(void* const* d_in, const int* in_sizes, int n_in,
                              void* d_out, int out_size, void* d_ws, size_t ws_size,
                              hipStream_t stream) {
    const float* x      = (const float*)d_in[0];
    const int*   edge   = (const int*)  d_in[1];
    const float* W1     = (const float*)d_in[2];
    const float* a_src1 = (const float*)d_in[3];
    const float* a_dst1 = (const float*)d_in[4];
    const float* b1     = (const float*)d_in[5];
    const float* W2     = (const float*)d_in[6];
    const float* a_src2 = (const float*)d_in[7];
    const float* a_dst2 = (const float*)d_in[8];
    const float* b2     = (const float*)d_in[9];

    constexpr size_t A = 256;
    auto al = [](size_t b) { return (b + A - 1) / A * A; };
    char* ws = (char*)d_ws;
    size_t off = 0;
    int*      flag   = (int*)(ws + off);      off += al(256);
    int*      ccnt   = (int*)(ws + off);      off += al((size_t)NCHUNK * NBUCK * 4); // 830 KB
    int*      bcnt   = (int*)(ws + off);      off += al(NBUCK * 4);
    int*      bbase  = (int*)(ws + off);      off += al((NBUCK + 1) * 4);
    unsigned* staged = (unsigned*)(ws + off); off += al((size_t)E_TOT * 4);          // 26 MB
    int*      csr    = (int*)(ws + off);      off += al((size_t)E_TOT * 4);          // 26 MB
    int*      offs   = (int*)(ws + off);      off += al((size_t)(N_NODES + 1) * 4);
    char*     rec    = (char*)(ws + off);     off += al((size_t)N_NODES * RECB);     // 6.4 MB
    float*    adst   = (float*)(ws + off);    off += al((size_t)N_NODES * 2 * 4);    // 0.8 MB
    float*    h2     = (float*)(ws + off);    off += al((size_t)N_NODES * 4);
    (void)ws_size; (void)in_sizes; (void)n_in; (void)out_size;

    k_detect<<<1, 64, 0, stream>>>(edge, flag);
    k_gemm1 <<<(N_NODES + 15) / 16, 256, 0, stream>>>(x, W1, a_src1, a_dst1, rec, adst);
    k_ccount<<<NCHUNK, 256, 0, stream>>>(edge, flag, ccnt);
    k_cscan <<<NBUCK, 256, 0, stream>>>(ccnt, bcnt);
    k_bscan <<<1, 256, 0, stream>>>(bcnt, bbase);
    k_bin   <<<NCHUNK, 256, 0, stream>>>(edge, flag, ccnt, bbase, staged);
    k_sort  <<<NBUCK * 2, 1024, 0, stream>>>(staged, bbase, csr, offs);
    k_edge1 <<<(N_NODES + 15) / 16, 256, 0, stream>>>(offs, csr, rec, adst, b1, W2, h2);
    k_edge2 <<<(N_NODES + 15) / 16, 256, 0, stream>>>(offs, csr, h2, a_src2, a_dst2, b2,
                                                      (float*)d_out);
}